// Round 1
// baseline (305.308 us; speedup 1.0000x reference)
//
#include <hip/hip_runtime.h>
#include <math.h>

#define S_ 1024
#define B_ 64
#define D_ 1024
#define O_ 512

__device__ __forceinline__ void add4(float4& a, const float4 v){ a.x+=v.x; a.y+=v.y; a.z+=v.z; a.w+=v.w; }
__device__ __forceinline__ void fma4(float4& a, const float w, const float4 v){ a.x+=w*v.x; a.y+=w*v.y; a.z+=w*v.z; a.w+=w*v.w; }

// ---------------------------------------------------------------------------
// Pass 1a: xsum[b][d] = sum_s x0[s][b][d]   (atomic partial sums over s-chunks)
// grid (B_, 16), block 256. Each block: one b, 64 s-values, full D via t*4.
// ---------------------------------------------------------------------------
__global__ __launch_bounds__(256) void k_sum(const float* __restrict__ x0,
                                             float* __restrict__ xsum){
  const int b = blockIdx.x, chunk = blockIdx.y, t = threadIdx.x;
  const int d4 = t*4;
  const float* base = x0 + (size_t)b*D_ + d4;
  float4 a0={0,0,0,0}, a1=a0, a2=a0, a3=a0;
  const int s0 = chunk*64;
  for (int s = s0; s < s0+64; s += 4){
    add4(a0, *(const float4*)(base + (size_t)(s+0)*(B_*D_)));
    add4(a1, *(const float4*)(base + (size_t)(s+1)*(B_*D_)));
    add4(a2, *(const float4*)(base + (size_t)(s+2)*(B_*D_)));
    add4(a3, *(const float4*)(base + (size_t)(s+3)*(B_*D_)));
  }
  add4(a0,a1); add4(a2,a3); add4(a0,a2);
  float* dst = xsum + b*D_ + d4;
  atomicAdd(dst+0, a0.x); atomicAdd(dst+1, a0.y);
  atomicAdd(dst+2, a0.z); atomicAdd(dst+3, a0.w);
}

// ---------------------------------------------------------------------------
// Pass 1b: invcnt[b] = 1 / sum_s x1[s][b].  grid 64, block 256.
// ---------------------------------------------------------------------------
__global__ __launch_bounds__(256) void k_cnt(const float* __restrict__ x1,
                                             float* __restrict__ invcnt){
  const int b = blockIdx.x, t = threadIdx.x;
  float s = 0.f;
  #pragma unroll
  for (int k = 0; k < 4; ++k) s += x1[(size_t)(t + k*256)*B_ + b];
  for (int m = 32; m >= 1; m >>= 1) s += __shfl_xor(s, m, 64);
  __shared__ float red[4];
  if ((t & 63) == 0) red[t >> 6] = s;
  __syncthreads();
  if (t == 0) invcnt[b] = 1.0f / (red[0] + red[1] + red[2] + red[3]);
}

// ---------------------------------------------------------------------------
// Small GEMM: Out[b][i] = act( bias[i] + sum_d In[b][d]*rowscale[b]*W[i][d] )
// In: B_ x D_ row-major, W: M x D_ row-major. 32x32 tile, K-chunk 64.
// grid (M/32, B_/32), block 256 (16x16, 2x2 acc per thread).
// ---------------------------------------------------------------------------
template<bool RELU>
__global__ __launch_bounds__(256) void k_gemm(const float* __restrict__ In,
                                              const float* __restrict__ W,
                                              const float* __restrict__ bias,
                                              const float* __restrict__ rowscale,
                                              float* __restrict__ Out, int M){
  __shared__ float sW[64][34];
  __shared__ float sIn[64][34];
  const int t = threadIdx.x;
  const int i0 = blockIdx.x * 32, b0 = blockIdx.y * 32;
  const int tx = t & 15, ty = t >> 4;
  float acc[2][2] = {{0.f,0.f},{0.f,0.f}};
  for (int k0 = 0; k0 < D_; k0 += 64){
    #pragma unroll
    for (int r = 0; r < 8; ++r){
      const int idx = t + r*256;
      const int kk = idx & 63, ii = idx >> 6;
      sW[kk][ii] = W[(size_t)(i0+ii)*D_ + k0 + kk];
    }
    #pragma unroll
    for (int r = 0; r < 8; ++r){
      const int idx = t + r*256;
      const int kk = idx & 63, bb = idx >> 6;
      float v = In[(size_t)(b0+bb)*D_ + k0 + kk];
      if (rowscale) v *= rowscale[b0+bb];
      sIn[kk][bb] = v;
    }
    __syncthreads();
    #pragma unroll
    for (int kk = 0; kk < 64; ++kk){
      const float2 w = *(const float2*)&sW[kk][ty*2];
      const float2 x = *(const float2*)&sIn[kk][tx*2];
      acc[0][0] += w.x*x.x; acc[0][1] += w.x*x.y;
      acc[1][0] += w.y*x.x; acc[1][1] += w.y*x.y;
    }
    __syncthreads();
  }
  #pragma unroll
  for (int a_ = 0; a_ < 2; ++a_)
    #pragma unroll
    for (int c_ = 0; c_ < 2; ++c_){
      const int i = i0 + ty*2 + a_, b = b0 + tx*2 + c_;
      float v = acc[a_][c_] + bias[i];
      if (RELU) v = fmaxf(v, 0.f);
      Out[(size_t)b*M + i] = v;
    }
}

// ---------------------------------------------------------------------------
// Pass 2: e[s*B+b] = dot(x0[s][b][:], q[b][:]);  exact 0 -> -inf (mask).
// One wave per row. grid S_*B_/4, block 256 (4 waves).
// ---------------------------------------------------------------------------
__global__ __launch_bounds__(256) void k_dote(const float* __restrict__ x0,
                                              const float* __restrict__ q,
                                              float* __restrict__ e){
  const int w = threadIdx.x >> 6, lane = threadIdx.x & 63;
  const int p = blockIdx.x*4 + w;           // p = s*B_ + b
  const int b = p & (B_-1);
  const float* row = x0 + (size_t)p*D_;
  const float* qr  = q  + (size_t)b*D_;
  float acc = 0.f;
  #pragma unroll
  for (int k = 0; k < 4; ++k){
    const int off = lane*4 + k*256;
    const float4 xv = *(const float4*)&row[off];
    const float4 qv = *(const float4*)&qr[off];
    acc += xv.x*qv.x + xv.y*qv.y + xv.z*qv.z + xv.w*qv.w;
  }
  for (int m = 32; m >= 1; m >>= 1) acc += __shfl_xor(acc, m, 64);
  if (lane == 0)
    e[p] = (acc == 0.0f) ? -__builtin_huge_valf() : acc;
}

// ---------------------------------------------------------------------------
// Pass 3: softmax over s per column b; writes output a[s*B+b].
// grid B_, block 256 (4 s-values per thread).
// ---------------------------------------------------------------------------
__global__ __launch_bounds__(256) void k_softmax(const float* __restrict__ e,
                                                 float* __restrict__ a){
  const int b = blockIdx.x, t = threadIdx.x;
  float v[4];
  #pragma unroll
  for (int k = 0; k < 4; ++k) v[k] = e[(size_t)(t + k*256)*B_ + b];
  float m = fmaxf(fmaxf(v[0],v[1]), fmaxf(v[2],v[3]));
  for (int msk = 32; msk >= 1; msk >>= 1) m = fmaxf(m, __shfl_xor(m, msk, 64));
  __shared__ float red[4];
  __shared__ float bcast;
  if ((t & 63) == 0) red[t >> 6] = m;
  __syncthreads();
  if (t == 0) bcast = fmaxf(fmaxf(red[0],red[1]), fmaxf(red[2],red[3]));
  __syncthreads();
  m = bcast;
  float ex[4]; float s = 0.f;
  #pragma unroll
  for (int k = 0; k < 4; ++k){ ex[k] = expf(v[k] - m); s += ex[k]; }
  for (int msk = 32; msk >= 1; msk >>= 1) s += __shfl_xor(s, msk, 64);
  __syncthreads();
  if ((t & 63) == 0) red[t >> 6] = s;
  __syncthreads();
  if (t == 0) bcast = red[0] + red[1] + red[2] + red[3];
  __syncthreads();
  const float inv = 1.0f / bcast;
  #pragma unroll
  for (int k = 0; k < 4; ++k) a[(size_t)(t + k*256)*B_ + b] = ex[k] * inv;
}

// ---------------------------------------------------------------------------
// Pass 4: y[b][d] = sum_s a[s*B+b] * x0[s][b][d]   (atomic over s-chunks)
// grid (B_, 16), block 256.
// ---------------------------------------------------------------------------
__global__ __launch_bounds__(256) void k_wsum(const float* __restrict__ x0,
                                              const float* __restrict__ a,
                                              float* __restrict__ y){
  const int b = blockIdx.x, chunk = blockIdx.y, t = threadIdx.x;
  const int d4 = t*4;
  const float* base = x0 + (size_t)b*D_ + d4;
  float4 a0={0,0,0,0}, a1=a0, a2=a0, a3=a0;
  const int s0 = chunk*64;
  for (int s = s0; s < s0+64; s += 4){
    const float w0 = a[(size_t)(s+0)*B_ + b];
    const float w1 = a[(size_t)(s+1)*B_ + b];
    const float w2 = a[(size_t)(s+2)*B_ + b];
    const float w3 = a[(size_t)(s+3)*B_ + b];
    fma4(a0, w0, *(const float4*)(base + (size_t)(s+0)*(B_*D_)));
    fma4(a1, w1, *(const float4*)(base + (size_t)(s+1)*(B_*D_)));
    fma4(a2, w2, *(const float4*)(base + (size_t)(s+2)*(B_*D_)));
    fma4(a3, w3, *(const float4*)(base + (size_t)(s+3)*(B_*D_)));
  }
  add4(a0,a1); add4(a2,a3); add4(a0,a2);
  float* dst = y + b*D_ + d4;
  atomicAdd(dst+0, a0.x); atomicAdd(dst+1, a0.y);
  atomicAdd(dst+2, a0.z); atomicAdd(dst+3, a0.w);
}

// ---------------------------------------------------------------------------
extern "C" void kernel_launch(void* const* d_in, const int* in_sizes, int n_in,
                              void* d_out, int out_size, void* d_ws, size_t ws_size,
                              hipStream_t stream){
  const float* x0 = (const float*)d_in[0];
  const float* x1 = (const float*)d_in[1];
  const float* Wq = (const float*)d_in[2];
  const float* bq = (const float*)d_in[3];
  const float* Wv = (const float*)d_in[4];
  const float* bv = (const float*)d_in[5];
  const float* Wc = (const float*)d_in[6];
  const float* bc = (const float*)d_in[7];

  float* out_p = (float*)d_out;              // (B, O) = 64x512
  float* a_p   = out_p + (size_t)B_*O_;      // (S, B, 1) = 1024x64

  float* ws     = (float*)d_ws;
  float* xsum   = ws;                        // B_*D_
  float* y      = ws + 1*B_*D_;              // B_*D_
  float* q      = ws + 2*B_*D_;              // B_*D_
  float* e      = ws + 3*B_*D_;              // S_*B_
  float* c      = ws + 4*B_*D_;              // B_*D_
  float* invcnt = ws + 5*B_*D_;              // B_

  // zero the two atomic accumulators (xsum, y)
  hipMemsetAsync(d_ws, 0, (size_t)2*B_*D_*sizeof(float), stream);

  k_cnt<<<B_, 256, 0, stream>>>(x1, invcnt);
  k_sum<<<dim3(B_, 16), 256, 0, stream>>>(x0, xsum);
  k_gemm<false><<<dim3(D_/32, B_/32), 256, 0, stream>>>(xsum, Wq, bq, invcnt, q, D_);
  k_dote<<<(S_*B_)/4, 256, 0, stream>>>(x0, q, e);
  k_softmax<<<B_, 256, 0, stream>>>(e, a_p);
  k_wsum<<<dim3(B_, 16), 256, 0, stream>>>(x0, a_p, y);
  k_gemm<false><<<dim3(D_/32, B_/32), 256, 0, stream>>>(y, Wv, bv, nullptr, c, D_);
  k_gemm<true ><<<dim3(O_/32, B_/32), 256, 0, stream>>>(c, Wc, bc, nullptr, out_p, O_);
}

// Round 2
// 294.958 us; speedup vs baseline: 1.0351x; 1.0351x over previous
//
#include <hip/hip_runtime.h>
#include <math.h>

#define S_ 1024
#define B_ 64
#define D_ 1024
#define O_ 512

__device__ __forceinline__ void add4(float4& a, const float4 v){ a.x+=v.x; a.y+=v.y; a.z+=v.z; a.w+=v.w; }
__device__ __forceinline__ void fma4(float4& a, const float w, const float4 v){ a.x+=w*v.x; a.y+=w*v.y; a.z+=w*v.z; a.w+=w*v.w; }

// ---------------------------------------------------------------------------
// Pass 1a: psum[chunk][b][d] = sum over 64 s of x0[s][b][d]  (no atomics)
// grid (B_, 16), block 256.
// ---------------------------------------------------------------------------
__global__ __launch_bounds__(256) void k_sum(const float* __restrict__ x0,
                                             float* __restrict__ psum){
  const int b = blockIdx.x, chunk = blockIdx.y, t = threadIdx.x;
  const int d4 = t*4;
  const float* base = x0 + (size_t)b*D_ + d4;
  float4 a0={0,0,0,0}, a1=a0, a2=a0, a3=a0;
  const int s0 = chunk*64;
  for (int s = s0; s < s0+64; s += 4){
    add4(a0, *(const float4*)(base + (size_t)(s+0)*(B_*D_)));
    add4(a1, *(const float4*)(base + (size_t)(s+1)*(B_*D_)));
    add4(a2, *(const float4*)(base + (size_t)(s+2)*(B_*D_)));
    add4(a3, *(const float4*)(base + (size_t)(s+3)*(B_*D_)));
  }
  add4(a0,a1); add4(a2,a3); add4(a0,a2);
  *(float4*)(psum + ((size_t)chunk*B_ + b)*D_ + d4) = a0;
}

// ---------------------------------------------------------------------------
// Reduce 16 partial planes: out[i] = sum_c part[c][i], i over B_*D_.
// grid 64, block 256 (float4 per thread).
// ---------------------------------------------------------------------------
__global__ __launch_bounds__(256) void k_reduce16(const float* __restrict__ part,
                                                  float* __restrict__ out){
  const size_t i = ((size_t)blockIdx.x*256 + threadIdx.x)*4;
  float4 a = *(const float4*)&part[i];
  #pragma unroll
  for (int c = 1; c < 16; ++c)
    add4(a, *(const float4*)&part[(size_t)c*B_*D_ + i]);
  *(float4*)&out[i] = a;
}

// ---------------------------------------------------------------------------
// Pass 1b: invcnt[b] = 1 / sum_s x1[s][b].  grid 64, block 256.
// ---------------------------------------------------------------------------
__global__ __launch_bounds__(256) void k_cnt(const float* __restrict__ x1,
                                             float* __restrict__ invcnt){
  const int b = blockIdx.x, t = threadIdx.x;
  float s = 0.f;
  #pragma unroll
  for (int k = 0; k < 4; ++k) s += x1[(size_t)(t + k*256)*B_ + b];
  for (int m = 32; m >= 1; m >>= 1) s += __shfl_xor(s, m, 64);
  __shared__ float red[4];
  if ((t & 63) == 0) red[t >> 6] = s;
  __syncthreads();
  if (t == 0) invcnt[b] = 1.0f / (red[0] + red[1] + red[2] + red[3]);
}

// ---------------------------------------------------------------------------
// Small GEMM: Out[b][i] = act( bias[i] + sum_d In[b][d]*rowscale[b]*W[i][d] )
// In: B_ x D_ row-major, W: M x D_ row-major. 32x32 tile, K-chunk 64.
// grid (M/32, B_/32), block 256 (16x16, 2x2 acc per thread).
// ---------------------------------------------------------------------------
template<bool RELU>
__global__ __launch_bounds__(256) void k_gemm(const float* __restrict__ In,
                                              const float* __restrict__ W,
                                              const float* __restrict__ bias,
                                              const float* __restrict__ rowscale,
                                              float* __restrict__ Out, int M){
  __shared__ float sW[64][34];
  __shared__ float sIn[64][34];
  const int t = threadIdx.x;
  const int i0 = blockIdx.x * 32, b0 = blockIdx.y * 32;
  const int tx = t & 15, ty = t >> 4;
  float acc[2][2] = {{0.f,0.f},{0.f,0.f}};
  for (int k0 = 0; k0 < D_; k0 += 64){
    #pragma unroll
    for (int r = 0; r < 8; ++r){
      const int idx = t + r*256;
      const int kk = idx & 63, ii = idx >> 6;
      sW[kk][ii] = W[(size_t)(i0+ii)*D_ + k0 + kk];
    }
    #pragma unroll
    for (int r = 0; r < 8; ++r){
      const int idx = t + r*256;
      const int kk = idx & 63, bb = idx >> 6;
      float v = In[(size_t)(b0+bb)*D_ + k0 + kk];
      if (rowscale) v *= rowscale[b0+bb];
      sIn[kk][bb] = v;
    }
    __syncthreads();
    #pragma unroll
    for (int kk = 0; kk < 64; ++kk){
      const float2 w = *(const float2*)&sW[kk][ty*2];
      const float2 x = *(const float2*)&sIn[kk][tx*2];
      acc[0][0] += w.x*x.x; acc[0][1] += w.x*x.y;
      acc[1][0] += w.y*x.x; acc[1][1] += w.y*x.y;
    }
    __syncthreads();
  }
  #pragma unroll
  for (int a_ = 0; a_ < 2; ++a_)
    #pragma unroll
    for (int c_ = 0; c_ < 2; ++c_){
      const int i = i0 + ty*2 + a_, b = b0 + tx*2 + c_;
      float v = acc[a_][c_] + bias[i];
      if (RELU) v = fmaxf(v, 0.f);
      Out[(size_t)b*M + i] = v;
    }
}

// ---------------------------------------------------------------------------
// Pass 2: e[s*B+b] = dot(x0[s][b][:], q[b][:]);  exact 0 -> -inf (mask).
// One wave per row. grid S_*B_/4, block 256 (4 waves).
// ---------------------------------------------------------------------------
__global__ __launch_bounds__(256) void k_dote(const float* __restrict__ x0,
                                              const float* __restrict__ q,
                                              float* __restrict__ e){
  const int w = threadIdx.x >> 6, lane = threadIdx.x & 63;
  const int p = blockIdx.x*4 + w;           // p = s*B_ + b
  const int b = p & (B_-1);
  const float* row = x0 + (size_t)p*D_;
  const float* qr  = q  + (size_t)b*D_;
  float acc = 0.f;
  #pragma unroll
  for (int k = 0; k < 4; ++k){
    const int off = lane*4 + k*256;
    const float4 xv = *(const float4*)&row[off];
    const float4 qv = *(const float4*)&qr[off];
    acc += xv.x*qv.x + xv.y*qv.y + xv.z*qv.z + xv.w*qv.w;
  }
  for (int m = 32; m >= 1; m >>= 1) acc += __shfl_xor(acc, m, 64);
  if (lane == 0)
    e[p] = (acc == 0.0f) ? -__builtin_huge_valf() : acc;
}

// ---------------------------------------------------------------------------
// Pass 3: softmax over s per column b; writes output a[s*B+b].
// grid B_, block 256 (4 s-values per thread).
// ---------------------------------------------------------------------------
__global__ __launch_bounds__(256) void k_softmax(const float* __restrict__ e,
                                                 float* __restrict__ a){
  const int b = blockIdx.x, t = threadIdx.x;
  float v[4];
  #pragma unroll
  for (int k = 0; k < 4; ++k) v[k] = e[(size_t)(t + k*256)*B_ + b];
  float m = fmaxf(fmaxf(v[0],v[1]), fmaxf(v[2],v[3]));
  for (int msk = 32; msk >= 1; msk >>= 1) m = fmaxf(m, __shfl_xor(m, msk, 64));
  __shared__ float red[4];
  __shared__ float bcast;
  if ((t & 63) == 0) red[t >> 6] = m;
  __syncthreads();
  if (t == 0) bcast = fmaxf(fmaxf(red[0],red[1]), fmaxf(red[2],red[3]));
  __syncthreads();
  m = bcast;
  float ex[4]; float s = 0.f;
  #pragma unroll
  for (int k = 0; k < 4; ++k){ ex[k] = expf(v[k] - m); s += ex[k]; }
  for (int msk = 32; msk >= 1; msk >>= 1) s += __shfl_xor(s, msk, 64);
  __syncthreads();
  if ((t & 63) == 0) red[t >> 6] = s;
  __syncthreads();
  if (t == 0) bcast = red[0] + red[1] + red[2] + red[3];
  __syncthreads();
  const float inv = 1.0f / bcast;
  #pragma unroll
  for (int k = 0; k < 4; ++k) a[(size_t)(t + k*256)*B_ + b] = ex[k] * inv;
}

// ---------------------------------------------------------------------------
// Pass 4: py[chunk][b][d] = sum over 64 s of a[s*B+b] * x0[s][b][d]
// grid (B_, 16), block 256.  (no atomics)
// ---------------------------------------------------------------------------
__global__ __launch_bounds__(256) void k_wsum(const float* __restrict__ x0,
                                              const float* __restrict__ a,
                                              float* __restrict__ py){
  const int b = blockIdx.x, chunk = blockIdx.y, t = threadIdx.x;
  const int d4 = t*4;
  const float* base = x0 + (size_t)b*D_ + d4;
  float4 a0={0,0,0,0}, a1=a0, a2=a0, a3=a0;
  const int s0 = chunk*64;
  for (int s = s0; s < s0+64; s += 4){
    const float w0 = a[(size_t)(s+0)*B_ + b];
    const float w1 = a[(size_t)(s+1)*B_ + b];
    const float w2 = a[(size_t)(s+2)*B_ + b];
    const float w3 = a[(size_t)(s+3)*B_ + b];
    fma4(a0, w0, *(const float4*)(base + (size_t)(s+0)*(B_*D_)));
    fma4(a1, w1, *(const float4*)(base + (size_t)(s+1)*(B_*D_)));
    fma4(a2, w2, *(const float4*)(base + (size_t)(s+2)*(B_*D_)));
    fma4(a3, w3, *(const float4*)(base + (size_t)(s+3)*(B_*D_)));
  }
  add4(a0,a1); add4(a2,a3); add4(a0,a2);
  *(float4*)(py + ((size_t)chunk*B_ + b)*D_ + d4) = a0;
}

// ---------------------------------------------------------------------------
extern "C" void kernel_launch(void* const* d_in, const int* in_sizes, int n_in,
                              void* d_out, int out_size, void* d_ws, size_t ws_size,
                              hipStream_t stream){
  const float* x0 = (const float*)d_in[0];
  const float* x1 = (const float*)d_in[1];
  const float* Wq = (const float*)d_in[2];
  const float* bq = (const float*)d_in[3];
  const float* Wv = (const float*)d_in[4];
  const float* bv = (const float*)d_in[5];
  const float* Wc = (const float*)d_in[6];
  const float* bc = (const float*)d_in[7];

  float* out_p = (float*)d_out;              // (B, O) = 64x512
  float* a_p   = out_p + (size_t)B_*O_;      // (S, B, 1) = 1024x64

  float* ws     = (float*)d_ws;
  float* psum   = ws;                        // 16*B_*D_
  float* py     = ws + (size_t)16*B_*D_;     // 16*B_*D_
  float* xsum   = ws + (size_t)32*B_*D_;     // B_*D_
  float* y      = ws + (size_t)33*B_*D_;     // B_*D_
  float* q      = ws + (size_t)34*B_*D_;     // B_*D_
  float* c      = ws + (size_t)35*B_*D_;     // B_*D_
  float* e      = ws + (size_t)36*B_*D_;     // S_*B_
  float* invcnt = ws + (size_t)37*B_*D_;     // B_

  k_cnt<<<B_, 256, 0, stream>>>(x1, invcnt);
  k_sum<<<dim3(B_, 16), 256, 0, stream>>>(x0, psum);
  k_reduce16<<<(B_*D_)/1024, 256, 0, stream>>>(psum, xsum);
  k_gemm<false><<<dim3(D_/32, B_/32), 256, 0, stream>>>(xsum, Wq, bq, invcnt, q, D_);
  k_dote<<<(S_*B_)/4, 256, 0, stream>>>(x0, q, e);
  k_softmax<<<B_, 256, 0, stream>>>(e, a_p);
  k_wsum<<<dim3(B_, 16), 256, 0, stream>>>(x0, a_p, py);
  k_reduce16<<<(B_*D_)/1024, 256, 0, stream>>>(py, y);
  k_gemm<false><<<dim3(D_/32, B_/32), 256, 0, stream>>>(y, Wv, bv, nullptr, c, D_);
  k_gemm<true ><<<dim3(O_/32, B_/32), 256, 0, stream>>>(c, Wc, bc, nullptr, out_p, O_);
}

// Round 3
// 292.240 us; speedup vs baseline: 1.0447x; 1.0093x over previous
//
#include <hip/hip_runtime.h>
#include <math.h>

#define S_ 1024
#define B_ 64
#define D_ 1024
#define O_ 512

typedef unsigned int uint_t;

__device__ __forceinline__ void add4(float4& a, const float4 v){ a.x+=v.x; a.y+=v.y; a.z+=v.z; a.w+=v.w; }

// bf16 helpers (bit-level, RNE pack / exact unpack)
__device__ __forceinline__ float bflo(uint_t u){ return __uint_as_float(u << 16); }
__device__ __forceinline__ float bfhi(uint_t u){ return __uint_as_float(u & 0xffff0000u); }
__device__ __forceinline__ uint_t bf1(float x){
  uint_t u = __float_as_uint(x);
  return (u + 0x7fffu + ((u >> 16) & 1u)) >> 16;           // round-nearest-even
}
__device__ __forceinline__ uint_t bfpack(float lo, float hi){ return bf1(lo) | (bf1(hi) << 16); }

// ---------------------------------------------------------------------------
// Pass 1a: psum[chunk][b][d] = sum over 64 s of x0[s][b][d]; also writes bf16
// copy of x0 into xh (same s,b,d layout, 2 elems per uint). grid (B_,16), 256.
// ---------------------------------------------------------------------------
__global__ __launch_bounds__(256) void k_sum_cvt(const float* __restrict__ x0,
                                                 float* __restrict__ psum,
                                                 uint_t* __restrict__ xh){
  const int b = blockIdx.x, chunk = blockIdx.y, t = threadIdx.x;
  const int d4 = t*4;
  const size_t rowoff = (size_t)b*D_ + d4;
  float4 a0={0,0,0,0}, a1=a0, a2=a0, a3=a0;
  const int s0 = chunk*64;
  for (int s = s0; s < s0+64; s += 4){
    const float4 v0 = *(const float4*)(x0 + (size_t)(s+0)*(B_*D_) + rowoff);
    const float4 v1 = *(const float4*)(x0 + (size_t)(s+1)*(B_*D_) + rowoff);
    const float4 v2 = *(const float4*)(x0 + (size_t)(s+2)*(B_*D_) + rowoff);
    const float4 v3 = *(const float4*)(x0 + (size_t)(s+3)*(B_*D_) + rowoff);
    add4(a0,v0); add4(a1,v1); add4(a2,v2); add4(a3,v3);
    *(uint2*)(xh + ((size_t)(s+0)*(B_*D_) + rowoff)/2) = make_uint2(bfpack(v0.x,v0.y), bfpack(v0.z,v0.w));
    *(uint2*)(xh + ((size_t)(s+1)*(B_*D_) + rowoff)/2) = make_uint2(bfpack(v1.x,v1.y), bfpack(v1.z,v1.w));
    *(uint2*)(xh + ((size_t)(s+2)*(B_*D_) + rowoff)/2) = make_uint2(bfpack(v2.x,v2.y), bfpack(v2.z,v2.w));
    *(uint2*)(xh + ((size_t)(s+3)*(B_*D_) + rowoff)/2) = make_uint2(bfpack(v3.x,v3.y), bfpack(v3.z,v3.w));
  }
  add4(a0,a1); add4(a2,a3); add4(a0,a2);
  *(float4*)(psum + ((size_t)chunk*B_ + b)*D_ + d4) = a0;
}

// ---------------------------------------------------------------------------
// Reduce 16 partial planes: out[i] = sum_c part[c][i], i over B_*D_.
// ---------------------------------------------------------------------------
__global__ __launch_bounds__(256) void k_reduce16(const float* __restrict__ part,
                                                  float* __restrict__ out){
  const size_t i = ((size_t)blockIdx.x*256 + threadIdx.x)*4;
  float4 a = *(const float4*)&part[i];
  #pragma unroll
  for (int c = 1; c < 16; ++c)
    add4(a, *(const float4*)&part[(size_t)c*B_*D_ + i]);
  *(float4*)&out[i] = a;
}

// ---------------------------------------------------------------------------
// Pass 1b: invcnt[b] = 1 / sum_s x1[s][b].  grid 64, block 256.
// ---------------------------------------------------------------------------
__global__ __launch_bounds__(256) void k_cnt(const float* __restrict__ x1,
                                             float* __restrict__ invcnt){
  const int b = blockIdx.x, t = threadIdx.x;
  float s = 0.f;
  #pragma unroll
  for (int k = 0; k < 4; ++k) s += x1[(size_t)(t + k*256)*B_ + b];
  for (int m = 32; m >= 1; m >>= 1) s += __shfl_xor(s, m, 64);
  __shared__ float red[4];
  if ((t & 63) == 0) red[t >> 6] = s;
  __syncthreads();
  if (t == 0) invcnt[b] = 1.0f / (red[0] + red[1] + red[2] + red[3]);
}

// ---------------------------------------------------------------------------
// Small GEMM: Out[b][i] = act( bias[i] + sum_d In[b][d]*rowscale[b]*W[i][d] )
// ---------------------------------------------------------------------------
template<bool RELU>
__global__ __launch_bounds__(256) void k_gemm(const float* __restrict__ In,
                                              const float* __restrict__ W,
                                              const float* __restrict__ bias,
                                              const float* __restrict__ rowscale,
                                              float* __restrict__ Out, int M){
  __shared__ float sW[64][34];
  __shared__ float sIn[64][34];
  const int t = threadIdx.x;
  const int i0 = blockIdx.x * 32, b0 = blockIdx.y * 32;
  const int tx = t & 15, ty = t >> 4;
  float acc[2][2] = {{0.f,0.f},{0.f,0.f}};
  for (int k0 = 0; k0 < D_; k0 += 64){
    #pragma unroll
    for (int r = 0; r < 8; ++r){
      const int idx = t + r*256;
      const int kk = idx & 63, ii = idx >> 6;
      sW[kk][ii] = W[(size_t)(i0+ii)*D_ + k0 + kk];
    }
    #pragma unroll
    for (int r = 0; r < 8; ++r){
      const int idx = t + r*256;
      const int kk = idx & 63, bb = idx >> 6;
      float v = In[(size_t)(b0+bb)*D_ + k0 + kk];
      if (rowscale) v *= rowscale[b0+bb];
      sIn[kk][bb] = v;
    }
    __syncthreads();
    #pragma unroll
    for (int kk = 0; kk < 64; ++kk){
      const float2 w = *(const float2*)&sW[kk][ty*2];
      const float2 x = *(const float2*)&sIn[kk][tx*2];
      acc[0][0] += w.x*x.x; acc[0][1] += w.x*x.y;
      acc[1][0] += w.y*x.x; acc[1][1] += w.y*x.y;
    }
    __syncthreads();
  }
  #pragma unroll
  for (int a_ = 0; a_ < 2; ++a_)
    #pragma unroll
    for (int c_ = 0; c_ < 2; ++c_){
      const int i = i0 + ty*2 + a_, b = b0 + tx*2 + c_;
      float v = acc[a_][c_] + bias[i];
      if (RELU) v = fmaxf(v, 0.f);
      Out[(size_t)b*M + i] = v;
    }
}

// ---------------------------------------------------------------------------
// Pass 2: e[s*B+b] = dot(xh[s][b][:], q[b][:]);  exact 0 -> -inf (mask).
// One wave per row, bf16 x0 copy. grid S_*B_/4, block 256 (4 waves).
// ---------------------------------------------------------------------------
__global__ __launch_bounds__(256) void k_dote(const uint_t* __restrict__ xh,
                                              const float* __restrict__ q,
                                              float* __restrict__ e){
  const int w = threadIdx.x >> 6, lane = threadIdx.x & 63;
  const int p = blockIdx.x*4 + w;           // p = s*B_ + b
  const int b = p & (B_-1);
  const uint_t* row = xh + (size_t)p*(D_/2);
  const float* qr  = q + (size_t)b*D_;
  float acc = 0.f;
  #pragma unroll
  for (int it = 0; it < 2; ++it){
    const int e0 = lane*8 + it*512;        // element index
    const uint4  xv = *(const uint4*)&row[e0/2];
    const float4 q0 = *(const float4*)&qr[e0];
    const float4 q1 = *(const float4*)&qr[e0+4];
    acc += bflo(xv.x)*q0.x + bfhi(xv.x)*q0.y + bflo(xv.y)*q0.z + bfhi(xv.y)*q0.w
         + bflo(xv.z)*q1.x + bfhi(xv.z)*q1.y + bflo(xv.w)*q1.z + bfhi(xv.w)*q1.w;
  }
  for (int m = 32; m >= 1; m >>= 1) acc += __shfl_xor(acc, m, 64);
  if (lane == 0)
    e[p] = (acc == 0.0f) ? -__builtin_huge_valf() : acc;
}

// ---------------------------------------------------------------------------
// Pass 3: softmax over s per column b; writes output a[s*B+b].
// ---------------------------------------------------------------------------
__global__ __launch_bounds__(256) void k_softmax(const float* __restrict__ e,
                                                 float* __restrict__ a){
  const int b = blockIdx.x, t = threadIdx.x;
  float v[4];
  #pragma unroll
  for (int k = 0; k < 4; ++k) v[k] = e[(size_t)(t + k*256)*B_ + b];
  float m = fmaxf(fmaxf(v[0],v[1]), fmaxf(v[2],v[3]));
  for (int msk = 32; msk >= 1; msk >>= 1) m = fmaxf(m, __shfl_xor(m, msk, 64));
  __shared__ float red[4];
  __shared__ float bcast;
  if ((t & 63) == 0) red[t >> 6] = m;
  __syncthreads();
  if (t == 0) bcast = fmaxf(fmaxf(red[0],red[1]), fmaxf(red[2],red[3]));
  __syncthreads();
  m = bcast;
  float ex[4]; float s = 0.f;
  #pragma unroll
  for (int k = 0; k < 4; ++k){ ex[k] = expf(v[k] - m); s += ex[k]; }
  for (int msk = 32; msk >= 1; msk >>= 1) s += __shfl_xor(s, msk, 64);
  __syncthreads();
  if ((t & 63) == 0) red[t >> 6] = s;
  __syncthreads();
  if (t == 0) bcast = red[0] + red[1] + red[2] + red[3];
  __syncthreads();
  const float inv = 1.0f / bcast;
  #pragma unroll
  for (int k = 0; k < 4; ++k) a[(size_t)(t + k*256)*B_ + b] = ex[k] * inv;
}

// ---------------------------------------------------------------------------
// Pass 4: py[chunk][b][d] = sum over 64 s of a[s*B+b] * xh[s][b][d]  (bf16 x0)
// grid (B_, 16), block 256.
// ---------------------------------------------------------------------------
__global__ __launch_bounds__(256) void k_wsum(const uint_t* __restrict__ xh,
                                              const float* __restrict__ a,
                                              float* __restrict__ py){
  const int b = blockIdx.x, chunk = blockIdx.y, t = threadIdx.x;
  const int d4 = t*4;
  const size_t rowoff2 = ((size_t)b*D_ + d4)/2;       // uint index
  float4 a0={0,0,0,0}, a1=a0, a2=a0, a3=a0;
  const int s0 = chunk*64;
  for (int s = s0; s < s0+64; s += 4){
    const float w0 = a[(size_t)(s+0)*B_ + b];
    const float w1 = a[(size_t)(s+1)*B_ + b];
    const float w2 = a[(size_t)(s+2)*B_ + b];
    const float w3 = a[(size_t)(s+3)*B_ + b];
    const uint2 u0 = *(const uint2*)(xh + (size_t)(s+0)*(B_*D_/2) + rowoff2);
    const uint2 u1 = *(const uint2*)(xh + (size_t)(s+1)*(B_*D_/2) + rowoff2);
    const uint2 u2 = *(const uint2*)(xh + (size_t)(s+2)*(B_*D_/2) + rowoff2);
    const uint2 u3 = *(const uint2*)(xh + (size_t)(s+3)*(B_*D_/2) + rowoff2);
    a0.x += w0*bflo(u0.x); a0.y += w0*bfhi(u0.x); a0.z += w0*bflo(u0.y); a0.w += w0*bfhi(u0.y);
    a1.x += w1*bflo(u1.x); a1.y += w1*bfhi(u1.x); a1.z += w1*bflo(u1.y); a1.w += w1*bfhi(u1.y);
    a2.x += w2*bflo(u2.x); a2.y += w2*bfhi(u2.x); a2.z += w2*bflo(u2.y); a2.w += w2*bfhi(u2.y);
    a3.x += w3*bflo(u3.x); a3.y += w3*bfhi(u3.x); a3.z += w3*bflo(u3.y); a3.w += w3*bfhi(u3.y);
  }
  add4(a0,a1); add4(a2,a3); add4(a0,a2);
  *(float4*)(py + ((size_t)chunk*B_ + b)*D_ + d4) = a0;
}

// ---------------------------------------------------------------------------
extern "C" void kernel_launch(void* const* d_in, const int* in_sizes, int n_in,
                              void* d_out, int out_size, void* d_ws, size_t ws_size,
                              hipStream_t stream){
  const float* x0 = (const float*)d_in[0];
  const float* x1 = (const float*)d_in[1];
  const float* Wq = (const float*)d_in[2];
  const float* bq = (const float*)d_in[3];
  const float* Wv = (const float*)d_in[4];
  const float* bv = (const float*)d_in[5];
  const float* Wc = (const float*)d_in[6];
  const float* bc = (const float*)d_in[7];

  float* out_p = (float*)d_out;              // (B, O) = 64x512
  float* a_p   = out_p + (size_t)B_*O_;      // (S, B, 1) = 1024x64

  uint_t* xh  = (uint_t*)d_ws;               // bf16 copy of x0: S*B*D/2 uints = 128 MB
  float* fbase = (float*)((char*)d_ws + (size_t)S_*B_*(D_/2)*sizeof(uint_t));
  float* psum   = fbase;                     // 16*B_*D_ (4 MB)
  float* py     = fbase + (size_t)16*B_*D_;  // 16*B_*D_
  float* xsum   = fbase + (size_t)32*B_*D_;  // B_*D_
  float* y      = fbase + (size_t)33*B_*D_;  // B_*D_
  float* q      = fbase + (size_t)34*B_*D_;  // B_*D_
  float* c      = fbase + (size_t)35*B_*D_;  // B_*D_
  float* e      = fbase + (size_t)36*B_*D_;  // S_*B_
  float* invcnt = fbase + (size_t)37*B_*D_;  // B_

  k_cnt<<<B_, 256, 0, stream>>>(x1, invcnt);
  k_sum_cvt<<<dim3(B_, 16), 256, 0, stream>>>(x0, psum, xh);
  k_reduce16<<<(B_*D_)/1024, 256, 0, stream>>>(psum, xsum);
  k_gemm<false><<<dim3(D_/32, B_/32), 256, 0, stream>>>(xsum, Wq, bq, invcnt, q, D_);
  k_dote<<<(S_*B_)/4, 256, 0, stream>>>(xh, q, e);
  k_softmax<<<B_, 256, 0, stream>>>(e, a_p);
  k_wsum<<<dim3(B_, 16), 256, 0, stream>>>(xh, a_p, py);
  k_reduce16<<<(B_*D_)/1024, 256, 0, stream>>>(py, y);
  k_gemm<false><<<dim3(D_/32, B_/32), 256, 0, stream>>>(y, Wv, bv, nullptr, c, D_);
  k_gemm<true ><<<dim3(O_/32, B_/32), 256, 0, stream>>>(c, Wc, bc, nullptr, out_p, O_);
}

// Round 5
// 292.004 us; speedup vs baseline: 1.0456x; 1.0008x over previous
//
#include <hip/hip_runtime.h>
#include <math.h>

#define S_ 1024
#define B_ 64
#define D_ 1024
#define O_ 512

typedef unsigned int uint_t;

__device__ __forceinline__ void add4(float4& a, const float4 v){ a.x+=v.x; a.y+=v.y; a.z+=v.z; a.w+=v.w; }

// bf16 helpers (bit-level, RNE pack / exact unpack)
__device__ __forceinline__ float bflo(uint_t u){ return __uint_as_float(u << 16); }
__device__ __forceinline__ float bfhi(uint_t u){ return __uint_as_float(u & 0xffff0000u); }
__device__ __forceinline__ uint_t bf1(float x){
  uint_t u = __float_as_uint(x);
  return (u + 0x7fffu + ((u >> 16) & 1u)) >> 16;           // round-nearest-even
}
__device__ __forceinline__ uint_t pack2(float lo, float hi){ return bf1(lo) | (bf1(hi) << 16); }

// ---------------------------------------------------------------------------
// Pass 1a: psum[chunk][b][d] = sum over 64 s of x0[s][b][d]; writes bf16 copy
// of x0 into xh ([s][b][d], 2 elems/uint). grid (B_,16), block 256.
// ---------------------------------------------------------------------------
__global__ __launch_bounds__(256) void k_sum_cvt(const float* __restrict__ x0,
                                                 float* __restrict__ psum,
                                                 uint_t* __restrict__ xh){
  const int b = blockIdx.x, chunk = blockIdx.y, t = threadIdx.x;
  const int d4 = t*4;
  const size_t rowoff = (size_t)b*D_ + d4;
  float4 a0={0,0,0,0}, a1=a0, a2=a0, a3=a0;
  const int s0 = chunk*64;
  for (int s = s0; s < s0+64; s += 4){
    const float4 v0 = *(const float4*)(x0 + (size_t)(s+0)*(B_*D_) + rowoff);
    const float4 v1 = *(const float4*)(x0 + (size_t)(s+1)*(B_*D_) + rowoff);
    const float4 v2 = *(const float4*)(x0 + (size_t)(s+2)*(B_*D_) + rowoff);
    const float4 v3 = *(const float4*)(x0 + (size_t)(s+3)*(B_*D_) + rowoff);
    add4(a0,v0); add4(a1,v1); add4(a2,v2); add4(a3,v3);
    *(uint2*)(xh + ((size_t)(s+0)*(B_*D_) + rowoff)/2) = make_uint2(pack2(v0.x,v0.y), pack2(v0.z,v0.w));
    *(uint2*)(xh + ((size_t)(s+1)*(B_*D_) + rowoff)/2) = make_uint2(pack2(v1.x,v1.y), pack2(v1.z,v1.w));
    *(uint2*)(xh + ((size_t)(s+2)*(B_*D_) + rowoff)/2) = make_uint2(pack2(v2.x,v2.y), pack2(v2.z,v2.w));
    *(uint2*)(xh + ((size_t)(s+3)*(B_*D_) + rowoff)/2) = make_uint2(pack2(v3.x,v3.y), pack2(v3.z,v3.w));
  }
  add4(a0,a1); add4(a2,a3); add4(a0,a2);
  *(float4*)(psum + ((size_t)chunk*B_ + b)*D_ + d4) = a0;
}

// ---------------------------------------------------------------------------
// Reduce 16 psum planes -> xsum. grid 64, block 256.
// ---------------------------------------------------------------------------
__global__ __launch_bounds__(256) void k_reduce16(const float* __restrict__ part,
                                                  float* __restrict__ out){
  const size_t i = ((size_t)blockIdx.x*256 + threadIdx.x)*4;
  float4 a = *(const float4*)&part[i];
  #pragma unroll
  for (int c = 1; c < 16; ++c)
    add4(a, *(const float4*)&part[(size_t)c*B_*D_ + i]);
  *(float4*)&out[i] = a;
}

// ---------------------------------------------------------------------------
// invcnt[b] = 1 / sum_s x1[s][b].  grid 64, block 256.
// ---------------------------------------------------------------------------
__global__ __launch_bounds__(256) void k_cnt(const float* __restrict__ x1,
                                             float* __restrict__ invcnt){
  const int b = blockIdx.x, t = threadIdx.x;
  float s = 0.f;
  #pragma unroll
  for (int k = 0; k < 4; ++k) s += x1[(size_t)(t + k*256)*B_ + b];
  for (int m = 32; m >= 1; m >>= 1) s += __shfl_xor(s, m, 64);
  __shared__ float red[4];
  if ((t & 63) == 0) red[t >> 6] = s;
  __syncthreads();
  if (t == 0) invcnt[b] = 1.0f / (red[0] + red[1] + red[2] + red[3]);
}

// ---------------------------------------------------------------------------
// Small GEMM: Out[b][i] = act( bias[i] + sum_d In[b][d]*rowscale[b]*W[i][d] )
// ---------------------------------------------------------------------------
template<bool RELU>
__global__ __launch_bounds__(256) void k_gemm(const float* __restrict__ In,
                                              const float* __restrict__ W,
                                              const float* __restrict__ bias,
                                              const float* __restrict__ rowscale,
                                              float* __restrict__ Out, int M){
  __shared__ float sW[64][34];
  __shared__ float sIn[64][34];
  const int t = threadIdx.x;
  const int i0 = blockIdx.x * 32, b0 = blockIdx.y * 32;
  const int tx = t & 15, ty = t >> 4;
  float acc[2][2] = {{0.f,0.f},{0.f,0.f}};
  for (int k0 = 0; k0 < D_; k0 += 64){
    #pragma unroll
    for (int r = 0; r < 8; ++r){
      const int idx = t + r*256;
      const int kk = idx & 63, ii = idx >> 6;
      sW[kk][ii] = W[(size_t)(i0+ii)*D_ + k0 + kk];
    }
    #pragma unroll
    for (int r = 0; r < 8; ++r){
      const int idx = t + r*256;
      const int kk = idx & 63, bb = idx >> 6;
      float v = In[(size_t)(b0+bb)*D_ + k0 + kk];
      if (rowscale) v *= rowscale[b0+bb];
      sIn[kk][bb] = v;
    }
    __syncthreads();
    #pragma unroll
    for (int kk = 0; kk < 64; ++kk){
      const float2 w = *(const float2*)&sW[kk][ty*2];
      const float2 x = *(const float2*)&sIn[kk][tx*2];
      acc[0][0] += w.x*x.x; acc[0][1] += w.x*x.y;
      acc[1][0] += w.y*x.x; acc[1][1] += w.y*x.y;
    }
    __syncthreads();
  }
  #pragma unroll
  for (int a_ = 0; a_ < 2; ++a_)
    #pragma unroll
    for (int c_ = 0; c_ < 2; ++c_){
      const int i = i0 + ty*2 + a_, b = b0 + tx*2 + c_;
      float v = acc[a_][c_] + bias[i];
      if (RELU) v = fmaxf(v, 0.f);
      Out[(size_t)b*M + i] = v;
    }
}

// ---------------------------------------------------------------------------
// Pass 2: e[s*B+b] = dot(xh[s][b][:], q[b][:]);  exact 0 -> -inf (mask).
// One wave per row. grid S_*B_/4, block 256.
// ---------------------------------------------------------------------------
__global__ __launch_bounds__(256) void k_dote(const uint_t* __restrict__ xh,
                                              const float* __restrict__ q,
                                              float* __restrict__ e){
  const int w = threadIdx.x >> 6, lane = threadIdx.x & 63;
  const int p = blockIdx.x*4 + w;           // p = s*B_ + b
  const int b = p & (B_-1);
  const uint_t* row = xh + (size_t)p*(D_/2);
  const float* qr  = q + (size_t)b*D_;
  float acc = 0.f;
  #pragma unroll
  for (int it = 0; it < 2; ++it){
    const int e0 = lane*8 + it*512;
    const uint4  xv = *(const uint4*)&row[e0/2];
    const float4 q0 = *(const float4*)&qr[e0];
    const float4 q1 = *(const float4*)&qr[e0+4];
    acc += bflo(xv.x)*q0.x + bfhi(xv.x)*q0.y + bflo(xv.y)*q0.z + bfhi(xv.y)*q0.w
         + bflo(xv.z)*q1.x + bfhi(xv.z)*q1.y + bflo(xv.w)*q1.z + bfhi(xv.w)*q1.w;
  }
  for (int m = 32; m >= 1; m >>= 1) acc += __shfl_xor(acc, m, 64);
  if (lane == 0)
    e[p] = (acc == 0.0f) ? -__builtin_huge_valf() : acc;
}

// ---------------------------------------------------------------------------
// Pass 3: softmax over s per column b; writes output a[s*B+b].
// ---------------------------------------------------------------------------
__global__ __launch_bounds__(256) void k_softmax(const float* __restrict__ e,
                                                 float* __restrict__ a){
  const int b = blockIdx.x, t = threadIdx.x;
  float v[4];
  #pragma unroll
  for (int k = 0; k < 4; ++k) v[k] = e[(size_t)(t + k*256)*B_ + b];
  float m = fmaxf(fmaxf(v[0],v[1]), fmaxf(v[2],v[3]));
  for (int msk = 32; msk >= 1; msk >>= 1) m = fmaxf(m, __shfl_xor(m, msk, 64));
  __shared__ float red[4];
  __shared__ float bcast;
  if ((t & 63) == 0) red[t >> 6] = m;
  __syncthreads();
  if (t == 0) bcast = fmaxf(fmaxf(red[0],red[1]), fmaxf(red[2],red[3]));
  __syncthreads();
  m = bcast;
  float ex[4]; float s = 0.f;
  #pragma unroll
  for (int k = 0; k < 4; ++k){ ex[k] = expf(v[k] - m); s += ex[k]; }
  for (int msk = 32; msk >= 1; msk >>= 1) s += __shfl_xor(s, msk, 64);
  __syncthreads();
  if ((t & 63) == 0) red[t >> 6] = s;
  __syncthreads();
  if (t == 0) bcast = red[0] + red[1] + red[2] + red[3];
  __syncthreads();
  const float inv = 1.0f / bcast;
  #pragma unroll
  for (int k = 0; k < 4; ++k) a[(size_t)(t + k*256)*B_ + b] = ex[k] * inv;
}

// ---------------------------------------------------------------------------
// Pass 4 (direct): y[b][2*d0u .. +128) = sum_s a[s*B+b] * xh[s][b][slice]
// grid (B_, 8): b, uint-slice of 64 (=128 d elems). block 256 = 4 waves,
// wave w handles s ≡ w (mod 4); cross-wave combine in LDS.
// ---------------------------------------------------------------------------
__global__ __launch_bounds__(256) void k_wsum(const uint_t* __restrict__ xh,
                                              const float* __restrict__ a,
                                              float* __restrict__ y){
  const int b = blockIdx.x;
  const int d0u = blockIdx.y * 64;          // uint index within row
  const int uidx = threadIdx.x & 63;
  const int soff = threadIdx.x >> 6;        // 0..3
  const size_t colbase = (size_t)b*(D_/2) + d0u + uidx;
  float2 acc0={0,0}, acc1={0,0}, acc2={0,0}, acc3={0,0};
  #pragma unroll 1
  for (int i = 0; i < 256; i += 4){
    const int sa = soff + (i+0)*4, sb = soff + (i+1)*4;
    const int sc = soff + (i+2)*4, sd = soff + (i+3)*4;
    const float wa = a[(size_t)sa*B_ + b];
    const float wb = a[(size_t)sb*B_ + b];
    const float wc = a[(size_t)sc*B_ + b];
    const float wd = a[(size_t)sd*B_ + b];
    const uint_t ua = xh[(size_t)sa*(B_*D_/2) + colbase];
    const uint_t ub = xh[(size_t)sb*(B_*D_/2) + colbase];
    const uint_t uc = xh[(size_t)sc*(B_*D_/2) + colbase];
    const uint_t ud = xh[(size_t)sd*(B_*D_/2) + colbase];
    acc0.x += wa*bflo(ua); acc0.y += wa*bfhi(ua);
    acc1.x += wb*bflo(ub); acc1.y += wb*bfhi(ub);
    acc2.x += wc*bflo(uc); acc2.y += wc*bfhi(uc);
    acc3.x += wd*bflo(ud); acc3.y += wd*bfhi(ud);
  }
  acc0.x += acc1.x + acc2.x + acc3.x;
  acc0.y += acc1.y + acc2.y + acc3.y;
  __shared__ float2 buf[4][64];
  buf[soff][uidx] = acc0;
  __syncthreads();
  if (soff == 0){
    float2 r = buf[0][uidx];
    r.x += buf[1][uidx].x + buf[2][uidx].x + buf[3][uidx].x;
    r.y += buf[1][uidx].y + buf[2][uidx].y + buf[3][uidx].y;
    ((float2*)y)[(size_t)b*(D_/2) + d0u + uidx] = r;
  }
}

// ---------------------------------------------------------------------------
extern "C" void kernel_launch(void* const* d_in, const int* in_sizes, int n_in,
                              void* d_out, int out_size, void* d_ws, size_t ws_size,
                              hipStream_t stream){
  const float* x0 = (const float*)d_in[0];
  const float* x1 = (const float*)d_in[1];
  const float* Wq = (const float*)d_in[2];
  const float* bq = (const float*)d_in[3];
  const float* Wv = (const float*)d_in[4];
  const float* bv = (const float*)d_in[5];
  const float* Wc = (const float*)d_in[6];
  const float* bc = (const float*)d_in[7];

  float* out_p = (float*)d_out;              // (B, O)
  float* a_p   = out_p + (size_t)B_*O_;      // (S, B, 1)

  uint_t* xh  = (uint_t*)d_ws;               // bf16 x0 copy: 128 MB
  float* fbase = (float*)((char*)d_ws + (size_t)S_*B_*(D_/2)*sizeof(uint_t));
  float* psum   = fbase;                     // 16*B_*D_
  float* xsum   = fbase + (size_t)16*B_*D_;  // B_*D_
  float* y      = fbase + (size_t)17*B_*D_;  // B_*D_
  float* q      = fbase + (size_t)18*B_*D_;  // B_*D_
  float* c      = fbase + (size_t)19*B_*D_;  // B_*D_
  float* e      = fbase + (size_t)20*B_*D_;  // S_*B_
  float* invcnt = fbase + (size_t)21*B_*D_;  // B_

  k_cnt<<<B_, 256, 0, stream>>>(x1, invcnt);
  k_sum_cvt<<<dim3(B_, 16), 256, 0, stream>>>(x0, psum, xh);
  k_reduce16<<<(B_*D_)/1024, 256, 0, stream>>>(psum, xsum);
  k_gemm<false><<<dim3(D_/32, B_/32), 256, 0, stream>>>(xsum, Wq, bq, invcnt, q, D_);
  k_dote<<<(S_*B_)/4, 256, 0, stream>>>(xh, q, e);
  k_softmax<<<B_, 256, 0, stream>>>(e, a_p);
  k_wsum<<<dim3(B_, 8), 256, 0, stream>>>(xh, a_p, y);
  k_gemm<false><<<dim3(D_/32, B_/32), 256, 0, stream>>>(y, Wv, bv, nullptr, c, D_);
  k_gemm<true ><<<dim3(O_/32, B_/32), 256, 0, stream>>>(c, Wc, bc, nullptr, out_p, O_);
}

// Round 6
// 285.847 us; speedup vs baseline: 1.0681x; 1.0215x over previous
//
#include <hip/hip_runtime.h>
#include <math.h>

#define S_ 1024
#define B_ 64
#define D_ 1024
#define O_ 512

typedef unsigned int uint_t;
typedef float f32x4 __attribute__((ext_vector_type(4)));

// bf16 helpers (bit-level, RNE pack / exact unpack)
__device__ __forceinline__ float bflo(uint_t u){ return __uint_as_float(u << 16); }
__device__ __forceinline__ float bfhi(uint_t u){ return __uint_as_float(u & 0xffff0000u); }
__device__ __forceinline__ uint_t bf1(float x){
  uint_t u = __float_as_uint(x);
  return (u + 0x7fffu + ((u >> 16) & 1u)) >> 16;           // round-nearest-even
}
__device__ __forceinline__ uint_t pack2(float lo, float hi){ return bf1(lo) | (bf1(hi) << 16); }

// ---------------------------------------------------------------------------
// Pass 1: psum[chunk][b][d] = sum over 64 s of x0[s][b][d]; writes bf16 copy
// of x0 into xh. x0 reads are NON-TEMPORAL (read-once) so xh stays L3-resident.
// grid (B_,16), block 256.
// ---------------------------------------------------------------------------
__global__ __launch_bounds__(256) void k_sum_cvt(const float* __restrict__ x0,
                                                 float* __restrict__ psum,
                                                 uint_t* __restrict__ xh){
  const int b = blockIdx.x, chunk = blockIdx.y, t = threadIdx.x;
  const int d4 = t*4;
  const size_t rowoff = (size_t)b*D_ + d4;
  f32x4 a0={0,0,0,0}, a1=a0, a2=a0, a3=a0;
  const int s0 = chunk*64;
  for (int s = s0; s < s0+64; s += 4){
    const f32x4 v0 = __builtin_nontemporal_load((const f32x4*)(x0 + (size_t)(s+0)*(B_*D_) + rowoff));
    const f32x4 v1 = __builtin_nontemporal_load((const f32x4*)(x0 + (size_t)(s+1)*(B_*D_) + rowoff));
    const f32x4 v2 = __builtin_nontemporal_load((const f32x4*)(x0 + (size_t)(s+2)*(B_*D_) + rowoff));
    const f32x4 v3 = __builtin_nontemporal_load((const f32x4*)(x0 + (size_t)(s+3)*(B_*D_) + rowoff));
    a0 += v0; a1 += v1; a2 += v2; a3 += v3;
    *(uint2*)(xh + ((size_t)(s+0)*(B_*D_) + rowoff)/2) = make_uint2(pack2(v0.x,v0.y), pack2(v0.z,v0.w));
    *(uint2*)(xh + ((size_t)(s+1)*(B_*D_) + rowoff)/2) = make_uint2(pack2(v1.x,v1.y), pack2(v1.z,v1.w));
    *(uint2*)(xh + ((size_t)(s+2)*(B_*D_) + rowoff)/2) = make_uint2(pack2(v2.x,v2.y), pack2(v2.z,v2.w));
    *(uint2*)(xh + ((size_t)(s+3)*(B_*D_) + rowoff)/2) = make_uint2(pack2(v3.x,v3.y), pack2(v3.z,v3.w));
  }
  a0 += a1; a2 += a3; a0 += a2;
  *(f32x4*)(psum + ((size_t)chunk*B_ + b)*D_ + d4) = a0;
}

// ---------------------------------------------------------------------------
// Fused: blocks 0..63 reduce 16 psum planes -> xsum; block 64 computes
// invcnt[b] = 1/sum_s x1[s][b]. grid 65, block 256.
// ---------------------------------------------------------------------------
__global__ __launch_bounds__(256) void k_reduce_cnt(const float* __restrict__ part,
                                                    const float* __restrict__ x1,
                                                    float* __restrict__ xsum,
                                                    float* __restrict__ invcnt){
  const int t = threadIdx.x;
  if (blockIdx.x == 64){
    const int b = t & 63;                   // 4 threads per b would race; use 64 threads only
    if (t < 64){
      float s = 0.f;
      for (int k = 0; k < S_; ++k) s += x1[(size_t)k*B_ + b];
      invcnt[b] = 1.0f / s;
    }
    return;
  }
  const size_t i = ((size_t)blockIdx.x*256 + t)*4;
  f32x4 a = *(const f32x4*)&part[i];
  #pragma unroll
  for (int c = 1; c < 16; ++c)
    a += *(const f32x4*)&part[(size_t)c*B_*D_ + i];
  *(f32x4*)&xsum[i] = a;
}

// ---------------------------------------------------------------------------
// Small GEMM: Out[b][i] = act( bias[i] + sum_d In[b][d]*rowscale[b]*W[i][d] )
// ---------------------------------------------------------------------------
template<bool RELU>
__global__ __launch_bounds__(256) void k_gemm(const float* __restrict__ In,
                                              const float* __restrict__ W,
                                              const float* __restrict__ bias,
                                              const float* __restrict__ rowscale,
                                              float* __restrict__ Out, int M){
  __shared__ float sW[64][34];
  __shared__ float sIn[64][34];
  const int t = threadIdx.x;
  const int i0 = blockIdx.x * 32, b0 = blockIdx.y * 32;
  const int tx = t & 15, ty = t >> 4;
  float acc[2][2] = {{0.f,0.f},{0.f,0.f}};
  for (int k0 = 0; k0 < D_; k0 += 64){
    #pragma unroll
    for (int r = 0; r < 8; ++r){
      const int idx = t + r*256;
      const int kk = idx & 63, ii = idx >> 6;
      sW[kk][ii] = W[(size_t)(i0+ii)*D_ + k0 + kk];
    }
    #pragma unroll
    for (int r = 0; r < 8; ++r){
      const int idx = t + r*256;
      const int kk = idx & 63, bb = idx >> 6;
      float v = In[(size_t)(b0+bb)*D_ + k0 + kk];
      if (rowscale) v *= rowscale[b0+bb];
      sIn[kk][bb] = v;
    }
    __syncthreads();
    #pragma unroll
    for (int kk = 0; kk < 64; ++kk){
      const float2 w = *(const float2*)&sW[kk][ty*2];
      const float2 x = *(const float2*)&sIn[kk][tx*2];
      acc[0][0] += w.x*x.x; acc[0][1] += w.x*x.y;
      acc[1][0] += w.y*x.x; acc[1][1] += w.y*x.y;
    }
    __syncthreads();
  }
  #pragma unroll
  for (int a_ = 0; a_ < 2; ++a_)
    #pragma unroll
    for (int c_ = 0; c_ < 2; ++c_){
      const int i = i0 + ty*2 + a_, b = b0 + tx*2 + c_;
      float v = acc[a_][c_] + bias[i];
      if (RELU) v = fmaxf(v, 0.f);
      Out[(size_t)b*M + i] = v;
    }
}

// ---------------------------------------------------------------------------
// Pass 2: e[s*B+b] = dot(xh[s][b][:], q[b][:]);  exact 0 -> -inf (mask).
// One wave per row. grid S_*B_/4, block 256.
// ---------------------------------------------------------------------------
__global__ __launch_bounds__(256) void k_dote(const uint_t* __restrict__ xh,
                                              const float* __restrict__ q,
                                              float* __restrict__ e){
  const int w = threadIdx.x >> 6, lane = threadIdx.x & 63;
  const int p = blockIdx.x*4 + w;           // p = s*B_ + b
  const int b = p & (B_-1);
  const uint_t* row = xh + (size_t)p*(D_/2);
  const float* qr  = q + (size_t)b*D_;
  float acc = 0.f;
  #pragma unroll
  for (int it = 0; it < 2; ++it){
    const int e0 = lane*8 + it*512;
    const uint4  xv = *(const uint4*)&row[e0/2];
    const float4 q0 = *(const float4*)&qr[e0];
    const float4 q1 = *(const float4*)&qr[e0+4];
    acc += bflo(xv.x)*q0.x + bfhi(xv.x)*q0.y + bflo(xv.y)*q0.z + bfhi(xv.y)*q0.w
         + bflo(xv.z)*q1.x + bfhi(xv.z)*q1.y + bflo(xv.w)*q1.z + bfhi(xv.w)*q1.w;
  }
  for (int m = 32; m >= 1; m >>= 1) acc += __shfl_xor(acc, m, 64);
  if (lane == 0)
    e[p] = (acc == 0.0f) ? -__builtin_huge_valf() : acc;
}

// ---------------------------------------------------------------------------
// Pass 3+4 fused: per (b, slice) block: recompute softmax of e[:,b] into LDS,
// slice-0 block also writes output a; then y[b][slice] = sum_s w[s]*xh[s][b][.]
// grid (B_, 8), block 256 = 4 waves (wave w: s ≡ w mod 4).
// ---------------------------------------------------------------------------
__global__ __launch_bounds__(256) void k_wsum_sm(const uint_t* __restrict__ xh,
                                                 const float* __restrict__ e,
                                                 float* __restrict__ a_out,
                                                 float* __restrict__ y){
  const int b = blockIdx.x;
  const int d0u = blockIdx.y * 64;          // uint index within row
  const int t = threadIdx.x;
  const int uidx = t & 63;
  const int soff = t >> 6;                  // 0..3
  __shared__ float wbuf[S_];
  __shared__ float red[4];

  // --- softmax over e[:, b] (redundant per block; deterministic) ---
  float v[4];
  #pragma unroll
  for (int k = 0; k < 4; ++k) v[k] = e[(size_t)(t + k*256)*B_ + b];
  float m = fmaxf(fmaxf(v[0],v[1]), fmaxf(v[2],v[3]));
  for (int msk = 32; msk >= 1; msk >>= 1) m = fmaxf(m, __shfl_xor(m, msk, 64));
  if ((t & 63) == 0) red[t >> 6] = m;
  __syncthreads();
  m = fmaxf(fmaxf(red[0],red[1]), fmaxf(red[2],red[3]));
  float ex[4]; float s = 0.f;
  #pragma unroll
  for (int k = 0; k < 4; ++k){ ex[k] = expf(v[k] - m); s += ex[k]; }
  for (int msk = 32; msk >= 1; msk >>= 1) s += __shfl_xor(s, msk, 64);
  __syncthreads();                           // red reuse
  if ((t & 63) == 0) red[t >> 6] = s;
  __syncthreads();
  const float inv = 1.0f / (red[0] + red[1] + red[2] + red[3]);
  #pragma unroll
  for (int k = 0; k < 4; ++k){
    const float w = ex[k] * inv;
    wbuf[t + k*256] = w;
    if (blockIdx.y == 0) a_out[(size_t)(t + k*256)*B_ + b] = w;
  }
  __syncthreads();

  // --- weighted sum ---
  const size_t colbase = (size_t)b*(D_/2) + d0u + uidx;
  float2 acc0={0,0}, acc1={0,0}, acc2={0,0}, acc3={0,0};
  #pragma unroll 1
  for (int i = 0; i < 256; i += 4){
    const int sa = soff + (i+0)*4, sb = soff + (i+1)*4;
    const int sc = soff + (i+2)*4, sd = soff + (i+3)*4;
    const float wa = wbuf[sa];
    const float wb = wbuf[sb];
    const float wc = wbuf[sc];
    const float wd = wbuf[sd];
    const uint_t ua = xh[(size_t)sa*(B_*D_/2) + colbase];
    const uint_t ub = xh[(size_t)sb*(B_*D_/2) + colbase];
    const uint_t uc = xh[(size_t)sc*(B_*D_/2) + colbase];
    const uint_t ud = xh[(size_t)sd*(B_*D_/2) + colbase];
    acc0.x += wa*bflo(ua); acc0.y += wa*bfhi(ua);
    acc1.x += wb*bflo(ub); acc1.y += wb*bfhi(ub);
    acc2.x += wc*bflo(uc); acc2.y += wc*bfhi(uc);
    acc3.x += wd*bflo(ud); acc3.y += wd*bfhi(ud);
  }
  acc0.x += acc1.x + acc2.x + acc3.x;
  acc0.y += acc1.y + acc2.y + acc3.y;
  __shared__ float2 buf[4][64];
  buf[soff][uidx] = acc0;
  __syncthreads();
  if (soff == 0){
    float2 r = buf[0][uidx];
    r.x += buf[1][uidx].x + buf[2][uidx].x + buf[3][uidx].x;
    r.y += buf[1][uidx].y + buf[2][uidx].y + buf[3][uidx].y;
    ((float2*)y)[(size_t)b*(D_/2) + d0u + uidx] = r;
  }
}

// ---------------------------------------------------------------------------
extern "C" void kernel_launch(void* const* d_in, const int* in_sizes, int n_in,
                              void* d_out, int out_size, void* d_ws, size_t ws_size,
                              hipStream_t stream){
  const float* x0 = (const float*)d_in[0];
  const float* x1 = (const float*)d_in[1];
  const float* Wq = (const float*)d_in[2];
  const float* bq = (const float*)d_in[3];
  const float* Wv = (const float*)d_in[4];
  const float* bv = (const float*)d_in[5];
  const float* Wc = (const float*)d_in[6];
  const float* bc = (const float*)d_in[7];

  float* out_p = (float*)d_out;              // (B, O)
  float* a_p   = out_p + (size_t)B_*O_;      // (S, B, 1)

  uint_t* xh  = (uint_t*)d_ws;               // bf16 x0 copy: 128 MB
  float* fbase = (float*)((char*)d_ws + (size_t)S_*B_*(D_/2)*sizeof(uint_t));
  float* psum   = fbase;                     // 16*B_*D_
  float* xsum   = fbase + (size_t)16*B_*D_;  // B_*D_
  float* y      = fbase + (size_t)17*B_*D_;  // B_*D_
  float* q      = fbase + (size_t)18*B_*D_;  // B_*D_
  float* c      = fbase + (size_t)19*B_*D_;  // B_*D_
  float* e      = fbase + (size_t)20*B_*D_;  // S_*B_
  float* invcnt = fbase + (size_t)21*B_*D_;  // B_

  k_sum_cvt<<<dim3(B_, 16), 256, 0, stream>>>(x0, psum, xh);
  k_reduce_cnt<<<65, 256, 0, stream>>>(psum, x1, xsum, invcnt);
  k_gemm<false><<<dim3(D_/32, B_/32), 256, 0, stream>>>(xsum, Wq, bq, invcnt, q, D_);
  k_dote<<<(S_*B_)/4, 256, 0, stream>>>(xh, q, e);
  k_wsum_sm<<<dim3(B_, 8), 256, 0, stream>>>(xh, e, a_p, y);
  k_gemm<false><<<dim3(D_/32, B_/32), 256, 0, stream>>>(y, Wv, bv, nullptr, c, D_);
  k_gemm<true ><<<dim3(O_/32, B_/32), 256, 0, stream>>>(c, Wc, bc, nullptr, out_p, O_);
}

// Round 7
// 279.316 us; speedup vs baseline: 1.0931x; 1.0234x over previous
//
#include <hip/hip_runtime.h>
#include <math.h>

#define S_ 1024
#define B_ 64
#define D_ 1024
#define O_ 512

typedef unsigned int uint_t;
typedef float f32x4 __attribute__((ext_vector_type(4)));

// bf16 helpers (bit-level, RNE pack / exact unpack)
__device__ __forceinline__ float bflo(uint_t u){ return __uint_as_float(u << 16); }
__device__ __forceinline__ float bfhi(uint_t u){ return __uint_as_float(u & 0xffff0000u); }
__device__ __forceinline__ uint_t bf1(float x){
  uint_t u = __float_as_uint(x);
  return (u + 0x7fffu + ((u >> 16) & 1u)) >> 16;           // round-nearest-even
}
__device__ __forceinline__ uint_t pack2(float lo, float hi){ return bf1(lo) | (bf1(hi) << 16); }

// ---------------------------------------------------------------------------
// invcnt[b] = 1 / sum_s x1[s][b].  grid 64, block 256. (parallel version)
// ---------------------------------------------------------------------------
__global__ __launch_bounds__(256) void k_cnt(const float* __restrict__ x1,
                                             float* __restrict__ invcnt){
  const int b = blockIdx.x, t = threadIdx.x;
  float s = 0.f;
  #pragma unroll
  for (int k = 0; k < 4; ++k) s += x1[(size_t)(t + k*256)*B_ + b];
  for (int m = 32; m >= 1; m >>= 1) s += __shfl_xor(s, m, 64);
  __shared__ float red[4];
  if ((t & 63) == 0) red[t >> 6] = s;
  __syncthreads();
  if (t == 0) invcnt[b] = 1.0f / (red[0] + red[1] + red[2] + red[3]);
}

// ---------------------------------------------------------------------------
// Pass 1: psum[chunk][b][d] = sum over 64 s of x0[s][b][d]; writes bf16 copy
// of x0 into xh (uint4 = 16B stores). x0 reads NON-TEMPORAL (read-once) so xh
// stays L3-resident. grid (B_,16), block 256: thread = (s-half, 8 d-elems).
// ---------------------------------------------------------------------------
__global__ __launch_bounds__(256) void k_sum_cvt(const float* __restrict__ x0,
                                                 float* __restrict__ psum,
                                                 uint_t* __restrict__ xh){
  const int b = blockIdx.x, chunk = blockIdx.y, t = threadIdx.x;
  const int d8 = (t & 127) * 8;
  const int shalf = t >> 7;                 // 0 or 1
  const size_t rowoff = (size_t)b*D_ + d8;
  f32x4 aLo = {0,0,0,0}, aHi = {0,0,0,0};
  const int s0 = chunk*64 + shalf*32;
  #pragma unroll 4
  for (int s = s0; s < s0+32; ++s){
    const float* p = x0 + (size_t)s*(B_*D_) + rowoff;
    const f32x4 vLo = __builtin_nontemporal_load((const f32x4*)p);
    const f32x4 vHi = __builtin_nontemporal_load((const f32x4*)(p+4));
    aLo += vLo; aHi += vHi;
    uint4 pk;
    pk.x = pack2(vLo.x, vLo.y); pk.y = pack2(vLo.z, vLo.w);
    pk.z = pack2(vHi.x, vHi.y); pk.w = pack2(vHi.z, vHi.w);
    *(uint4*)(xh + ((size_t)s*(B_*D_) + rowoff)/2) = pk;
  }
  __shared__ f32x4 lds[128][2];
  if (shalf){ lds[t & 127][0] = aLo; lds[t & 127][1] = aHi; }
  __syncthreads();
  if (!shalf){
    aLo += lds[t][0]; aHi += lds[t][1];
    float* dst = psum + ((size_t)chunk*B_ + b)*D_ + d8;
    *(f32x4*)dst = aLo;
    *(f32x4*)(dst+4) = aHi;
  }
}

// ---------------------------------------------------------------------------
// Reduce 16 psum planes -> xsum. grid 64, block 256.
// ---------------------------------------------------------------------------
__global__ __launch_bounds__(256) void k_reduce16(const float* __restrict__ part,
                                                  float* __restrict__ out){
  const size_t i = ((size_t)blockIdx.x*256 + threadIdx.x)*4;
  f32x4 a = *(const f32x4*)&part[i];
  #pragma unroll
  for (int c = 1; c < 16; ++c)
    a += *(const f32x4*)&part[(size_t)c*B_*D_ + i];
  *(f32x4*)&out[i] = a;
}

// ---------------------------------------------------------------------------
// Small GEMM: Out[b][i] = act( bias[i] + sum_d In[b][d]*rowscale[b]*W[i][d] )
// ---------------------------------------------------------------------------
template<bool RELU>
__global__ __launch_bounds__(256) void k_gemm(const float* __restrict__ In,
                                              const float* __restrict__ W,
                                              const float* __restrict__ bias,
                                              const float* __restrict__ rowscale,
                                              float* __restrict__ Out, int M){
  __shared__ float sW[64][34];
  __shared__ float sIn[64][34];
  const int t = threadIdx.x;
  const int i0 = blockIdx.x * 32, b0 = blockIdx.y * 32;
  const int tx = t & 15, ty = t >> 4;
  float acc[2][2] = {{0.f,0.f},{0.f,0.f}};
  for (int k0 = 0; k0 < D_; k0 += 64){
    #pragma unroll
    for (int r = 0; r < 8; ++r){
      const int idx = t + r*256;
      const int kk = idx & 63, ii = idx >> 6;
      sW[kk][ii] = W[(size_t)(i0+ii)*D_ + k0 + kk];
    }
    #pragma unroll
    for (int r = 0; r < 8; ++r){
      const int idx = t + r*256;
      const int kk = idx & 63, bb = idx >> 6;
      float v = In[(size_t)(b0+bb)*D_ + k0 + kk];
      if (rowscale) v *= rowscale[b0+bb];
      sIn[kk][bb] = v;
    }
    __syncthreads();
    #pragma unroll
    for (int kk = 0; kk < 64; ++kk){
      const float2 w = *(const float2*)&sW[kk][ty*2];
      const float2 x = *(const float2*)&sIn[kk][tx*2];
      acc[0][0] += w.x*x.x; acc[0][1] += w.x*x.y;
      acc[1][0] += w.y*x.x; acc[1][1] += w.y*x.y;
    }
    __syncthreads();
  }
  #pragma unroll
  for (int a_ = 0; a_ < 2; ++a_)
    #pragma unroll
    for (int c_ = 0; c_ < 2; ++c_){
      const int i = i0 + ty*2 + a_, b = b0 + tx*2 + c_;
      float v = acc[a_][c_] + bias[i];
      if (RELU) v = fmaxf(v, 0.f);
      Out[(size_t)b*M + i] = v;
    }
}

// ---------------------------------------------------------------------------
// Pass 2: e[s*B+b] = dot(xh[s][b][:], q[b][:]);  exact 0 -> -inf (mask).
// One wave per row. grid S_*B_/4, block 256.
// ---------------------------------------------------------------------------
__global__ __launch_bounds__(256) void k_dote(const uint_t* __restrict__ xh,
                                              const float* __restrict__ q,
                                              float* __restrict__ e){
  const int w = threadIdx.x >> 6, lane = threadIdx.x & 63;
  const int p = blockIdx.x*4 + w;           // p = s*B_ + b
  const int b = p & (B_-1);
  const uint_t* row = xh + (size_t)p*(D_/2);
  const float* qr  = q + (size_t)b*D_;
  float acc = 0.f;
  #pragma unroll
  for (int it = 0; it < 2; ++it){
    const int e0 = lane*8 + it*512;
    const uint4  xv = *(const uint4*)&row[e0/2];
    const float4 q0 = *(const float4*)&qr[e0];
    const float4 q1 = *(const float4*)&qr[e0+4];
    acc += bflo(xv.x)*q0.x + bfhi(xv.x)*q0.y + bflo(xv.y)*q0.z + bfhi(xv.y)*q0.w
         + bflo(xv.z)*q1.x + bfhi(xv.z)*q1.y + bflo(xv.w)*q1.z + bfhi(xv.w)*q1.w;
  }
  for (int m = 32; m >= 1; m >>= 1) acc += __shfl_xor(acc, m, 64);
  if (lane == 0)
    e[p] = (acc == 0.0f) ? -__builtin_huge_valf() : acc;
}

// ---------------------------------------------------------------------------
// Pass 3+4 fused: per (b, slice) block: recompute softmax of e[:,b] into LDS,
// slice-0 block also writes output a; then y[b][slice] = sum_s w[s]*xh[s][b][.]
// grid (B_, 8), block 256 = 4 waves (wave w: s ≡ w mod 4).
// ---------------------------------------------------------------------------
__global__ __launch_bounds__(256) void k_wsum_sm(const uint_t* __restrict__ xh,
                                                 const float* __restrict__ e,
                                                 float* __restrict__ a_out,
                                                 float* __restrict__ y){
  const int b = blockIdx.x;
  const int d0u = blockIdx.y * 64;          // uint index within row
  const int t = threadIdx.x;
  const int uidx = t & 63;
  const int soff = t >> 6;                  // 0..3
  __shared__ float wbuf[S_];
  __shared__ float red[4];

  // --- softmax over e[:, b] (redundant per block; deterministic) ---
  float v[4];
  #pragma unroll
  for (int k = 0; k < 4; ++k) v[k] = e[(size_t)(t + k*256)*B_ + b];
  float m = fmaxf(fmaxf(v[0],v[1]), fmaxf(v[2],v[3]));
  for (int msk = 32; msk >= 1; msk >>= 1) m = fmaxf(m, __shfl_xor(m, msk, 64));
  if ((t & 63) == 0) red[t >> 6] = m;
  __syncthreads();
  m = fmaxf(fmaxf(red[0],red[1]), fmaxf(red[2],red[3]));
  float ex[4]; float s = 0.f;
  #pragma unroll
  for (int k = 0; k < 4; ++k){ ex[k] = expf(v[k] - m); s += ex[k]; }
  for (int msk = 32; msk >= 1; msk >>= 1) s += __shfl_xor(s, msk, 64);
  __syncthreads();                           // red reuse
  if ((t & 63) == 0) red[t >> 6] = s;
  __syncthreads();
  const float inv = 1.0f / (red[0] + red[1] + red[2] + red[3]);
  #pragma unroll
  for (int k = 0; k < 4; ++k){
    const float w = ex[k] * inv;
    wbuf[t + k*256] = w;
    if (blockIdx.y == 0) a_out[(size_t)(t + k*256)*B_ + b] = w;
  }
  __syncthreads();

  // --- weighted sum ---
  const size_t colbase = (size_t)b*(D_/2) + d0u + uidx;
  float2 acc0={0,0}, acc1={0,0}, acc2={0,0}, acc3={0,0};
  #pragma unroll 1
  for (int i = 0; i < 256; i += 4){
    const int sa = soff + (i+0)*4, sb = soff + (i+1)*4;
    const int sc = soff + (i+2)*4, sd = soff + (i+3)*4;
    const float wa = wbuf[sa];
    const float wb = wbuf[sb];
    const float wc = wbuf[sc];
    const float wd = wbuf[sd];
    const uint_t ua = xh[(size_t)sa*(B_*D_/2) + colbase];
    const uint_t ub = xh[(size_t)sb*(B_*D_/2) + colbase];
    const uint_t uc = xh[(size_t)sc*(B_*D_/2) + colbase];
    const uint_t ud = xh[(size_t)sd*(B_*D_/2) + colbase];
    acc0.x += wa*bflo(ua); acc0.y += wa*bfhi(ua);
    acc1.x += wb*bflo(ub); acc1.y += wb*bfhi(ub);
    acc2.x += wc*bflo(uc); acc2.y += wc*bfhi(uc);
    acc3.x += wd*bflo(ud); acc3.y += wd*bfhi(ud);
  }
  acc0.x += acc1.x + acc2.x + acc3.x;
  acc0.y += acc1.y + acc2.y + acc3.y;
  __shared__ float2 buf[4][64];
  buf[soff][uidx] = acc0;
  __syncthreads();
  if (soff == 0){
    float2 r = buf[0][uidx];
    r.x += buf[1][uidx].x + buf[2][uidx].x + buf[3][uidx].x;
    r.y += buf[1][uidx].y + buf[2][uidx].y + buf[3][uidx].y;
    ((float2*)y)[(size_t)b*(D_/2) + d0u + uidx] = r;
  }
}

// ---------------------------------------------------------------------------
extern "C" void kernel_launch(void* const* d_in, const int* in_sizes, int n_in,
                              void* d_out, int out_size, void* d_ws, size_t ws_size,
                              hipStream_t stream){
  const float* x0 = (const float*)d_in[0];
  const float* x1 = (const float*)d_in[1];
  const float* Wq = (const float*)d_in[2];
  const float* bq = (const float*)d_in[3];
  const float* Wv = (const float*)d_in[4];
  const float* bv = (const float*)d_in[5];
  const float* Wc = (const float*)d_in[6];
  const float* bc = (const float*)d_in[7];

  float* out_p = (float*)d_out;              // (B, O)
  float* a_p   = out_p + (size_t)B_*O_;      // (S, B, 1)

  uint_t* xh  = (uint_t*)d_ws;               // bf16 x0 copy: 128 MB
  float* fbase = (float*)((char*)d_ws + (size_t)S_*B_*(D_/2)*sizeof(uint_t));
  float* psum   = fbase;                     // 16*B_*D_
  float* xsum   = fbase + (size_t)16*B_*D_;  // B_*D_
  float* y      = fbase + (size_t)17*B_*D_;  // B_*D_
  float* q      = fbase + (size_t)18*B_*D_;  // B_*D_
  float* c      = fbase + (size_t)19*B_*D_;  // B_*D_
  float* e      = fbase + (size_t)20*B_*D_;  // S_*B_
  float* invcnt = fbase + (size_t)21*B_*D_;  // B_

  k_cnt<<<B_, 256, 0, stream>>>(x1, invcnt);
  k_sum_cvt<<<dim3(B_, 16), 256, 0, stream>>>(x0, psum, xh);
  k_reduce16<<<(B_*D_)/1024, 256, 0, stream>>>(psum, xsum);
  k_gemm<false><<<dim3(D_/32, B_/32), 256, 0, stream>>>(xsum, Wq, bq, invcnt, q, D_);
  k_dote<<<(S_*B_)/4, 256, 0, stream>>>(xh, q, e);
  k_wsum_sm<<<dim3(B_, 8), 256, 0, stream>>>(xh, e, a_p, y);
  k_gemm<false><<<dim3(D_/32, B_/32), 256, 0, stream>>>(y, Wv, bv, nullptr, c, D_);
  k_gemm<true ><<<dim3(O_/32, B_/32), 256, 0, stream>>>(c, Wc, bc, nullptr, out_p, O_);
}

// Round 8
// 268.080 us; speedup vs baseline: 1.1389x; 1.0419x over previous
//
#include <hip/hip_runtime.h>
#include <hip/hip_bf16.h>
#include <math.h>

#define S_ 1024
#define B_ 64
#define D_ 1024
#define O_ 512

typedef unsigned int uint_t;
typedef float f32x4 __attribute__((ext_vector_type(4)));

// bf16 unpack (exact, bit-level)
__device__ __forceinline__ float bflo(uint_t u){ return __uint_as_float(u << 16); }
__device__ __forceinline__ float bfhi(uint_t u){ return __uint_as_float(u & 0xffff0000u); }
// bf16 pack via HW convert (v_cvt_pk_bf16_f32 path, RNE — same numerics as bit-math)
__device__ __forceinline__ uint_t pack2(float lo, float hi){
  __hip_bfloat16 bl = __float2bfloat16(lo);
  __hip_bfloat16 bh = __float2bfloat16(hi);
  const unsigned short ul = *reinterpret_cast<unsigned short*>(&bl);
  const unsigned short uh = *reinterpret_cast<unsigned short*>(&bh);
  return (uint_t)ul | ((uint_t)uh << 16);
}

// ---------------------------------------------------------------------------
// Pass 1: psum[chunk][b][d] = sum over 64 s of x0[s][b][d]; writes bf16 copy
// of x0 into xh (uint4 = 16B stores). x0 reads NON-TEMPORAL (read-once) so xh
// stays L3-resident. grid (B_,16), block 256: thread = (s-half, 8 d-elems).
// ---------------------------------------------------------------------------
__global__ __launch_bounds__(256) void k_sum_cvt(const float* __restrict__ x0,
                                                 float* __restrict__ psum,
                                                 uint_t* __restrict__ xh){
  const int b = blockIdx.x, chunk = blockIdx.y, t = threadIdx.x;
  const int d8 = (t & 127) * 8;
  const int shalf = t >> 7;                 // 0 or 1
  const size_t rowoff = (size_t)b*D_ + d8;
  f32x4 aLo = {0,0,0,0}, aHi = {0,0,0,0};
  const int s0 = chunk*64 + shalf*32;
  #pragma unroll 4
  for (int s = s0; s < s0+32; ++s){
    const float* p = x0 + (size_t)s*(B_*D_) + rowoff;
    const f32x4 vLo = __builtin_nontemporal_load((const f32x4*)p);
    const f32x4 vHi = __builtin_nontemporal_load((const f32x4*)(p+4));
    aLo += vLo; aHi += vHi;
    uint4 pk;
    pk.x = pack2(vLo.x, vLo.y); pk.y = pack2(vLo.z, vLo.w);
    pk.z = pack2(vHi.x, vHi.y); pk.w = pack2(vHi.z, vHi.w);
    *(uint4*)(xh + ((size_t)s*(B_*D_) + rowoff)/2) = pk;
  }
  __shared__ f32x4 lds[128][2];
  if (shalf){ lds[t & 127][0] = aLo; lds[t & 127][1] = aHi; }
  __syncthreads();
  if (!shalf){
    aLo += lds[t][0]; aHi += lds[t][1];
    float* dst = psum + ((size_t)chunk*B_ + b)*D_ + d8;
    *(f32x4*)dst = aLo;
    *(f32x4*)(dst+4) = aHi;
  }
}

// ---------------------------------------------------------------------------
// Fused: blocks 0..63 reduce 16 psum planes -> xsum; blocks 64..127: block
// 64+b computes invcnt[b] = 1/sum_s x1[s][b] (full 256-thread reduction).
// grid 128, block 256.
// ---------------------------------------------------------------------------
__global__ __launch_bounds__(256) void k_reduce_cnt(const float* __restrict__ part,
                                                    const float* __restrict__ x1,
                                                    float* __restrict__ xsum,
                                                    float* __restrict__ invcnt){
  const int t = threadIdx.x;
  if (blockIdx.x >= 64){
    const int b = blockIdx.x - 64;
    float s = 0.f;
    #pragma unroll
    for (int k = 0; k < 4; ++k) s += x1[(size_t)(t + k*256)*B_ + b];
    for (int m = 32; m >= 1; m >>= 1) s += __shfl_xor(s, m, 64);
    __shared__ float red[4];
    if ((t & 63) == 0) red[t >> 6] = s;
    __syncthreads();
    if (t == 0) invcnt[b] = 1.0f / (red[0] + red[1] + red[2] + red[3]);
    return;
  }
  const size_t i = ((size_t)blockIdx.x*256 + t)*4;
  f32x4 a = *(const f32x4*)&part[i];
  #pragma unroll
  for (int c = 1; c < 16; ++c)
    a += *(const f32x4*)&part[(size_t)c*B_*D_ + i];
  *(f32x4*)&xsum[i] = a;
}

// ---------------------------------------------------------------------------
// Small GEMM: Out[b][i] = act( bias[i] + sum_d In[b][d]*rowscale[b]*W[i][d] )
// ---------------------------------------------------------------------------
template<bool RELU>
__global__ __launch_bounds__(256) void k_gemm(const float* __restrict__ In,
                                              const float* __restrict__ W,
                                              const float* __restrict__ bias,
                                              const float* __restrict__ rowscale,
                                              float* __restrict__ Out, int M){
  __shared__ float sW[64][34];
  __shared__ float sIn[64][34];
  const int t = threadIdx.x;
  const int i0 = blockIdx.x * 32, b0 = blockIdx.y * 32;
  const int tx = t & 15, ty = t >> 4;
  float acc[2][2] = {{0.f,0.f},{0.f,0.f}};
  for (int k0 = 0; k0 < D_; k0 += 64){
    #pragma unroll
    for (int r = 0; r < 8; ++r){
      const int idx = t + r*256;
      const int kk = idx & 63, ii = idx >> 6;
      sW[kk][ii] = W[(size_t)(i0+ii)*D_ + k0 + kk];
    }
    #pragma unroll
    for (int r = 0; r < 8; ++r){
      const int idx = t + r*256;
      const int kk = idx & 63, bb = idx >> 6;
      float v = In[(size_t)(b0+bb)*D_ + k0 + kk];
      if (rowscale) v *= rowscale[b0+bb];
      sIn[kk][bb] = v;
    }
    __syncthreads();
    #pragma unroll
    for (int kk = 0; kk < 64; ++kk){
      const float2 w = *(const float2*)&sW[kk][ty*2];
      const float2 x = *(const float2*)&sIn[kk][tx*2];
      acc[0][0] += w.x*x.x; acc[0][1] += w.x*x.y;
      acc[1][0] += w.y*x.x; acc[1][1] += w.y*x.y;
    }
    __syncthreads();
  }
  #pragma unroll
  for (int a_ = 0; a_ < 2; ++a_)
    #pragma unroll
    for (int c_ = 0; c_ < 2; ++c_){
      const int i = i0 + ty*2 + a_, b = b0 + tx*2 + c_;
      float v = acc[a_][c_] + bias[i];
      if (RELU) v = fmaxf(v, 0.f);
      Out[(size_t)b*M + i] = v;
    }
}

// ---------------------------------------------------------------------------
// Pass 2: e[s*B+b] = dot(xh[s][b][:], q[b][:]);  exact 0 -> -inf (mask).
// One wave per row. grid S_*B_/4, block 256.
// ---------------------------------------------------------------------------
__global__ __launch_bounds__(256) void k_dote(const uint_t* __restrict__ xh,
                                              const float* __restrict__ q,
                                              float* __restrict__ e){
  const int w = threadIdx.x >> 6, lane = threadIdx.x & 63;
  const int p = blockIdx.x*4 + w;           // p = s*B_ + b
  const int b = p & (B_-1);
  const uint_t* row = xh + (size_t)p*(D_/2);
  const float* qr  = q + (size_t)b*D_;
  float acc = 0.f;
  #pragma unroll
  for (int it = 0; it < 2; ++it){
    const int e0 = lane*8 + it*512;
    const uint4  xv = *(const uint4*)&row[e0/2];
    const float4 q0 = *(const float4*)&qr[e0];
    const float4 q1 = *(const float4*)&qr[e0+4];
    acc += bflo(xv.x)*q0.x + bfhi(xv.x)*q0.y + bflo(xv.y)*q0.z + bfhi(xv.y)*q0.w
         + bflo(xv.z)*q1.x + bfhi(xv.z)*q1.y + bflo(xv.w)*q1.z + bfhi(xv.w)*q1.w;
  }
  for (int m = 32; m >= 1; m >>= 1) acc += __shfl_xor(acc, m, 64);
  if (lane == 0)
    e[p] = (acc == 0.0f) ? -__builtin_huge_valf() : acc;
}

// ---------------------------------------------------------------------------
// Pass 3+4 fused: per (b, slice) block: recompute softmax of e[:,b] into LDS,
// slice-0 block also writes output a; then y[b][slice] = sum_s w[s]*xh[s][b][.]
// grid (B_, 8), block 256 = 4 waves (wave w: s ≡ w mod 4), 8-deep unroll.
// ---------------------------------------------------------------------------
__global__ __launch_bounds__(256) void k_wsum_sm(const uint_t* __restrict__ xh,
                                                 const float* __restrict__ e,
                                                 float* __restrict__ a_out,
                                                 float* __restrict__ y){
  const int b = blockIdx.x;
  const int d0u = blockIdx.y * 64;          // uint index within row
  const int t = threadIdx.x;
  const int uidx = t & 63;
  const int soff = t >> 6;                  // 0..3
  __shared__ float wbuf[S_];
  __shared__ float red[4];

  // --- softmax over e[:, b] (redundant per block; deterministic) ---
  float v[4];
  #pragma unroll
  for (int k = 0; k < 4; ++k) v[k] = e[(size_t)(t + k*256)*B_ + b];
  float m = fmaxf(fmaxf(v[0],v[1]), fmaxf(v[2],v[3]));
  for (int msk = 32; msk >= 1; msk >>= 1) m = fmaxf(m, __shfl_xor(m, msk, 64));
  if ((t & 63) == 0) red[t >> 6] = m;
  __syncthreads();
  m = fmaxf(fmaxf(red[0],red[1]), fmaxf(red[2],red[3]));
  float ex[4]; float s = 0.f;
  #pragma unroll
  for (int k = 0; k < 4; ++k){ ex[k] = expf(v[k] - m); s += ex[k]; }
  for (int msk = 32; msk >= 1; msk >>= 1) s += __shfl_xor(s, msk, 64);
  __syncthreads();                           // red reuse
  if ((t & 63) == 0) red[t >> 6] = s;
  __syncthreads();
  const float inv = 1.0f / (red[0] + red[1] + red[2] + red[3]);
  #pragma unroll
  for (int k = 0; k < 4; ++k){
    const float w = ex[k] * inv;
    wbuf[t + k*256] = w;
    if (blockIdx.y == 0) a_out[(size_t)(t + k*256)*B_ + b] = w;
  }
  __syncthreads();

  // --- weighted sum (8 outstanding loads per thread) ---
  const size_t colbase = (size_t)b*(D_/2) + d0u + uidx;
  float2 acc0={0,0}, acc1={0,0}, acc2={0,0}, acc3={0,0};
  float2 acc4={0,0}, acc5={0,0}, acc6={0,0}, acc7={0,0};
  #pragma unroll 1
  for (int i = 0; i < 256; i += 8){
    const float w0 = wbuf[soff + (i+0)*4];
    const float w1 = wbuf[soff + (i+1)*4];
    const float w2 = wbuf[soff + (i+2)*4];
    const float w3 = wbuf[soff + (i+3)*4];
    const float w4 = wbuf[soff + (i+4)*4];
    const float w5 = wbuf[soff + (i+5)*4];
    const float w6 = wbuf[soff + (i+6)*4];
    const float w7 = wbuf[soff + (i+7)*4];
    const uint_t u0 = xh[(size_t)(soff + (i+0)*4)*(B_*D_/2) + colbase];
    const uint_t u1 = xh[(size_t)(soff + (i+1)*4)*(B_*D_/2) + colbase];
    const uint_t u2 = xh[(size_t)(soff + (i+2)*4)*(B_*D_/2) + colbase];
    const uint_t u3 = xh[(size_t)(soff + (i+3)*4)*(B_*D_/2) + colbase];
    const uint_t u4 = xh[(size_t)(soff + (i+4)*4)*(B_*D_/2) + colbase];
    const uint_t u5 = xh[(size_t)(soff + (i+5)*4)*(B_*D_/2) + colbase];
    const uint_t u6 = xh[(size_t)(soff + (i+6)*4)*(B_*D_/2) + colbase];
    const uint_t u7 = xh[(size_t)(soff + (i+7)*4)*(B_*D_/2) + colbase];
    acc0.x += w0*bflo(u0); acc0.y += w0*bfhi(u0);
    acc1.x += w1*bflo(u1); acc1.y += w1*bfhi(u1);
    acc2.x += w2*bflo(u2); acc2.y += w2*bfhi(u2);
    acc3.x += w3*bflo(u3); acc3.y += w3*bfhi(u3);
    acc4.x += w4*bflo(u4); acc4.y += w4*bfhi(u4);
    acc5.x += w5*bflo(u5); acc5.y += w5*bfhi(u5);
    acc6.x += w6*bflo(u6); acc6.y += w6*bfhi(u6);
    acc7.x += w7*bflo(u7); acc7.y += w7*bfhi(u7);
  }
  acc0.x += acc1.x; acc2.x += acc3.x; acc4.x += acc5.x; acc6.x += acc7.x;
  acc0.x += acc2.x; acc4.x += acc6.x; acc0.x += acc4.x;
  acc0.y += acc1.y; acc2.y += acc3.y; acc4.y += acc5.y; acc6.y += acc7.y;
  acc0.y += acc2.y; acc4.y += acc6.y; acc0.y += acc4.y;
  __shared__ float2 buf[4][64];
  buf[soff][uidx] = acc0;
  __syncthreads();
  if (soff == 0){
    float2 r = buf[0][uidx];
    r.x += buf[1][uidx].x + buf[2][uidx].x + buf[3][uidx].x;
    r.y += buf[1][uidx].y + buf[2][uidx].y + buf[3][uidx].y;
    ((float2*)y)[(size_t)b*(D_/2) + d0u + uidx] = r;
  }
}

// ---------------------------------------------------------------------------
extern "C" void kernel_launch(void* const* d_in, const int* in_sizes, int n_in,
                              void* d_out, int out_size, void* d_ws, size_t ws_size,
                              hipStream_t stream){
  const float* x0 = (const float*)d_in[0];
  const float* x1 = (const float*)d_in[1];
  const float* Wq = (const float*)d_in[2];
  const float* bq = (const float*)d_in[3];
  const float* Wv = (const float*)d_in[4];
  const float* bv = (const float*)d_in[5];
  const float* Wc = (const float*)d_in[6];
  const float* bc = (const float*)d_in[7];

  float* out_p = (float*)d_out;              // (B, O)
  float* a_p   = out_p + (size_t)B_*O_;      // (S, B, 1)

  uint_t* xh  = (uint_t*)d_ws;               // bf16 x0 copy: 128 MB
  float* fbase = (float*)((char*)d_ws + (size_t)S_*B_*(D_/2)*sizeof(uint_t));
  float* psum   = fbase;                     // 16*B_*D_
  float* xsum   = fbase + (size_t)16*B_*D_;  // B_*D_
  float* y      = fbase + (size_t)17*B_*D_;  // B_*D_
  float* q      = fbase + (size_t)18*B_*D_;  // B_*D_
  float* c      = fbase + (size_t)19*B_*D_;  // B_*D_
  float* e      = fbase + (size_t)20*B_*D_;  // S_*B_
  float* invcnt = fbase + (size_t)21*B_*D_;  // B_

  k_sum_cvt<<<dim3(B_, 16), 256, 0, stream>>>(x0, psum, xh);
  k_reduce_cnt<<<128, 256, 0, stream>>>(psum, x1, xsum, invcnt);
  k_gemm<false><<<dim3(D_/32, B_/32), 256, 0, stream>>>(xsum, Wq, bq, invcnt, q, D_);
  k_dote<<<(S_*B_)/4, 256, 0, stream>>>(xh, q, e);
  k_wsum_sm<<<dim3(B_, 8), 256, 0, stream>>>(xh, e, a_p, y);
  k_gemm<false><<<dim3(D_/32, B_/32), 256, 0, stream>>>(y, Wv, bv, nullptr, c, D_);
  k_gemm<true ><<<dim3(O_/32, B_/32), 256, 0, stream>>>(c, Wc, bc, nullptr, out_p, O_);
}

// Round 9
// 215.017 us; speedup vs baseline: 1.4199x; 1.2468x over previous
//
#include <hip/hip_runtime.h>
#include <hip/hip_bf16.h>
#include <math.h>

#define S_ 1024
#define B_ 64
#define D_ 1024
#define O_ 512

typedef unsigned int uint_t;
typedef float f32x4 __attribute__((ext_vector_type(4)));

// bf16 unpack (exact, bit-level)
__device__ __forceinline__ float bflo(uint_t u){ return __uint_as_float(u << 16); }
__device__ __forceinline__ float bfhi(uint_t u){ return __uint_as_float(u & 0xffff0000u); }
// bf16 pack via HW convert (v_cvt_pk_bf16_f32 path, RNE)
__device__ __forceinline__ uint_t pack2(float lo, float hi){
  __hip_bfloat16 bl = __float2bfloat16(lo);
  __hip_bfloat16 bh = __float2bfloat16(hi);
  const unsigned short ul = *reinterpret_cast<unsigned short*>(&bl);
  const unsigned short uh = *reinterpret_cast<unsigned short*>(&bh);
  return (uint_t)ul | ((uint_t)uh << 16);
}

// ---------------------------------------------------------------------------
// Pass 1: psum[chunk][b][d] = sum over 64 s of x0[s][b][d]; writes bf16 copy
// of x0 into xh (uint4 = 16B stores). x0 reads NON-TEMPORAL (read-once) so xh
// stays L3-resident. grid (B_,16), block 256: thread = (s-half, 8 d-elems).
// ---------------------------------------------------------------------------
__global__ __launch_bounds__(256) void k_sum_cvt(const float* __restrict__ x0,
                                                 float* __restrict__ psum,
                                                 uint_t* __restrict__ xh){
  const int b = blockIdx.x, chunk = blockIdx.y, t = threadIdx.x;
  const int d8 = (t & 127) * 8;
  const int shalf = t >> 7;                 // 0 or 1
  const size_t rowoff = (size_t)b*D_ + d8;
  f32x4 aLo = {0,0,0,0}, aHi = {0,0,0,0};
  const int s0 = chunk*64 + shalf*32;
  #pragma unroll 4
  for (int s = s0; s < s0+32; ++s){
    const float* p = x0 + (size_t)s*(B_*D_) + rowoff;
    const f32x4 vLo = __builtin_nontemporal_load((const f32x4*)p);
    const f32x4 vHi = __builtin_nontemporal_load((const f32x4*)(p+4));
    aLo += vLo; aHi += vHi;
    uint4 pk;
    pk.x = pack2(vLo.x, vLo.y); pk.y = pack2(vLo.z, vLo.w);
    pk.z = pack2(vHi.x, vHi.y); pk.w = pack2(vHi.z, vHi.w);
    *(uint4*)(xh + ((size_t)s*(B_*D_) + rowoff)/2) = pk;
  }
  __shared__ f32x4 lds[128][2];
  if (shalf){ lds[t & 127][0] = aLo; lds[t & 127][1] = aHi; }
  __syncthreads();
  if (!shalf){
    aLo += lds[t][0]; aHi += lds[t][1];
    float* dst = psum + ((size_t)chunk*B_ + b)*D_ + d8;
    *(f32x4*)dst = aLo;
    *(f32x4*)(dst+4) = aHi;
  }
}

// ---------------------------------------------------------------------------
// Fused: blocks 0..63 reduce 16 psum planes -> xsum; blocks 64..127: block
// 64+b computes invcnt[b] = 1/sum_s x1[s][b]. grid 128, block 256.
// ---------------------------------------------------------------------------
__global__ __launch_bounds__(256) void k_reduce_cnt(const float* __restrict__ part,
                                                    const float* __restrict__ x1,
                                                    float* __restrict__ xsum,
                                                    float* __restrict__ invcnt){
  const int t = threadIdx.x;
  if (blockIdx.x >= 64){
    const int b = blockIdx.x - 64;
    float s = 0.f;
    #pragma unroll
    for (int k = 0; k < 4; ++k) s += x1[(size_t)(t + k*256)*B_ + b];
    for (int m = 32; m >= 1; m >>= 1) s += __shfl_xor(s, m, 64);
    __shared__ float red[4];
    if ((t & 63) == 0) red[t >> 6] = s;
    __syncthreads();
    if (t == 0) invcnt[b] = 1.0f / (red[0] + red[1] + red[2] + red[3]);
    return;
  }
  const size_t i = ((size_t)blockIdx.x*256 + t)*4;
  f32x4 a = *(const f32x4*)&part[i];
  #pragma unroll
  for (int c = 1; c < 16; ++c)
    a += *(const f32x4*)&part[(size_t)c*B_*D_ + i];
  *(f32x4*)&xsum[i] = a;
}

// ---------------------------------------------------------------------------
// Small GEMM, in-block K-split: Out[b][i] = act(bias[i] + sum_d In*rs*W).
// 1024 threads = 4 K-groups x 256; each group: 32x32 tile over K-quarter in
// its own LDS partition; deterministic LDS combine at the end.
// grid (M/32, B_/32).
// ---------------------------------------------------------------------------
template<bool RELU>
__global__ __launch_bounds__(1024) void k_gemm(const float* __restrict__ In,
                                               const float* __restrict__ W,
                                               const float* __restrict__ bias,
                                               const float* __restrict__ rowscale,
                                               float* __restrict__ Out, int M){
  __shared__ float sW[4][64][34];   // ~34 KB
  __shared__ float sIn[4][64][34];  // ~34 KB
  const int t  = threadIdx.x & 255;
  const int kg = threadIdx.x >> 8;        // 0..3
  const int i0 = blockIdx.x * 32, b0 = blockIdx.y * 32;
  const int tx = t & 15, ty = t >> 4;
  float acc[2][2] = {{0.f,0.f},{0.f,0.f}};
  const int kbase = kg*256;
  for (int k0 = kbase; k0 < kbase+256; k0 += 64){
    #pragma unroll
    for (int r = 0; r < 8; ++r){
      const int idx = t + r*256;
      const int kk = idx & 63, ii = idx >> 6;
      sW[kg][kk][ii] = W[(size_t)(i0+ii)*D_ + k0 + kk];
    }
    #pragma unroll
    for (int r = 0; r < 8; ++r){
      const int idx = t + r*256;
      const int kk = idx & 63, bb = idx >> 6;
      float v = In[(size_t)(b0+bb)*D_ + k0 + kk];
      if (rowscale) v *= rowscale[b0+bb];
      sIn[kg][kk][bb] = v;
    }
    __syncthreads();
    #pragma unroll
    for (int kk = 0; kk < 64; ++kk){
      const float2 w = *(const float2*)&sW[kg][kk][ty*2];
      const float2 x = *(const float2*)&sIn[kg][kk][tx*2];
      acc[0][0] += w.x*x.x; acc[0][1] += w.x*x.y;
      acc[1][0] += w.y*x.x; acc[1][1] += w.y*x.y;
    }
    __syncthreads();
  }
  // combine the 4 K-group partials (reuse sW as scratch; all compute done)
  float* red = (float*)sW;                 // 4096 floats used
  #pragma unroll
  for (int a_ = 0; a_ < 2; ++a_)
    #pragma unroll
    for (int c_ = 0; c_ < 2; ++c_)
      red[(kg*256 + t)*4 + a_*2 + c_] = acc[a_][c_];
  __syncthreads();
  if (kg == 0){
    #pragma unroll
    for (int a_ = 0; a_ < 2; ++a_)
      #pragma unroll
      for (int c_ = 0; c_ < 2; ++c_){
        const int base = t*4 + a_*2 + c_;
        float v = red[base] + red[1024+base] + red[2048+base] + red[3072+base];
        const int i = i0 + ty*2 + a_, b = b0 + tx*2 + c_;
        v += bias[i];
        if (RELU) v = fmaxf(v, 0.f);
        Out[(size_t)b*M + i] = v;
      }
  }
}

// ---------------------------------------------------------------------------
// Pass 2: e[s*B+b] = dot(xh[s][b][:], q[b][:]);  exact 0 -> -inf (mask).
// One wave per row. grid S_*B_/4, block 256.
// ---------------------------------------------------------------------------
__global__ __launch_bounds__(256) void k_dote(const uint_t* __restrict__ xh,
                                              const float* __restrict__ q,
                                              float* __restrict__ e){
  const int w = threadIdx.x >> 6, lane = threadIdx.x & 63;
  const int p = blockIdx.x*4 + w;           // p = s*B_ + b
  const int b = p & (B_-1);
  const uint_t* row = xh + (size_t)p*(D_/2);
  const float* qr  = q + (size_t)b*D_;
  float acc = 0.f;
  #pragma unroll
  for (int it = 0; it < 2; ++it){
    const int e0 = lane*8 + it*512;
    const uint4  xv = *(const uint4*)&row[e0/2];
    const float4 q0 = *(const float4*)&qr[e0];
    const float4 q1 = *(const float4*)&qr[e0+4];
    acc += bflo(xv.x)*q0.x + bfhi(xv.x)*q0.y + bflo(xv.y)*q0.z + bfhi(xv.y)*q0.w
         + bflo(xv.z)*q1.x + bfhi(xv.z)*q1.y + bflo(xv.w)*q1.z + bfhi(xv.w)*q1.w;
  }
  for (int m = 32; m >= 1; m >>= 1) acc += __shfl_xor(acc, m, 64);
  if (lane == 0)
    e[p] = (acc == 0.0f) ? -__builtin_huge_valf() : acc;
}

// ---------------------------------------------------------------------------
// Pass 3+4 fused: per (b, slice) block: recompute softmax of e[:,b] into LDS,
// slice-0 block also writes output a; then y[b][slice] = sum_s w[s]*xh[s][b][.]
// grid (B_, 8), block 256 = 4 waves (wave w: s ≡ w mod 4), 8-deep unroll.
// ---------------------------------------------------------------------------
__global__ __launch_bounds__(256) void k_wsum_sm(const uint_t* __restrict__ xh,
                                                 const float* __restrict__ e,
                                                 float* __restrict__ a_out,
                                                 float* __restrict__ y){
  const int b = blockIdx.x;
  const int d0u = blockIdx.y * 64;          // uint index within row
  const int t = threadIdx.x;
  const int uidx = t & 63;
  const int soff = t >> 6;                  // 0..3
  __shared__ float wbuf[S_];
  __shared__ float red[4];

  // --- softmax over e[:, b] (redundant per block; deterministic) ---
  float v[4];
  #pragma unroll
  for (int k = 0; k < 4; ++k) v[k] = e[(size_t)(t + k*256)*B_ + b];
  float m = fmaxf(fmaxf(v[0],v[1]), fmaxf(v[2],v[3]));
  for (int msk = 32; msk >= 1; msk >>= 1) m = fmaxf(m, __shfl_xor(m, msk, 64));
  if ((t & 63) == 0) red[t >> 6] = m;
  __syncthreads();
  m = fmaxf(fmaxf(red[0],red[1]), fmaxf(red[2],red[3]));
  float ex[4]; float s = 0.f;
  #pragma unroll
  for (int k = 0; k < 4; ++k){ ex[k] = expf(v[k] - m); s += ex[k]; }
  for (int msk = 32; msk >= 1; msk >>= 1) s += __shfl_xor(s, msk, 64);
  __syncthreads();                           // red reuse
  if ((t & 63) == 0) red[t >> 6] = s;
  __syncthreads();
  const float inv = 1.0f / (red[0] + red[1] + red[2] + red[3]);
  #pragma unroll
  for (int k = 0; k < 4; ++k){
    const float w = ex[k] * inv;
    wbuf[t + k*256] = w;
    if (blockIdx.y == 0) a_out[(size_t)(t + k*256)*B_ + b] = w;
  }
  __syncthreads();

  // --- weighted sum (8 outstanding loads per thread) ---
  const size_t colbase = (size_t)b*(D_/2) + d0u + uidx;
  float2 acc0={0,0}, acc1={0,0}, acc2={0,0}, acc3={0,0};
  float2 acc4={0,0}, acc5={0,0}, acc6={0,0}, acc7={0,0};
  #pragma unroll 1
  for (int i = 0; i < 256; i += 8){
    const float w0 = wbuf[soff + (i+0)*4];
    const float w1 = wbuf[soff + (i+1)*4];
    const float w2 = wbuf[soff + (i+2)*4];
    const float w3 = wbuf[soff + (i+3)*4];
    const float w4 = wbuf[soff + (i+4)*4];
    const float w5 = wbuf[soff + (i+5)*4];
    const float w6 = wbuf[soff + (i+6)*4];
    const float w7 = wbuf[soff + (i+7)*4];
    const uint_t u0 = xh[(size_t)(soff + (i+0)*4)*(B_*D_/2) + colbase];
    const uint_t u1 = xh[(size_t)(soff + (i+1)*4)*(B_*D_/2) + colbase];
    const uint_t u2 = xh[(size_t)(soff + (i+2)*4)*(B_*D_/2) + colbase];
    const uint_t u3 = xh[(size_t)(soff + (i+3)*4)*(B_*D_/2) + colbase];
    const uint_t u4 = xh[(size_t)(soff + (i+4)*4)*(B_*D_/2) + colbase];
    const uint_t u5 = xh[(size_t)(soff + (i+5)*4)*(B_*D_/2) + colbase];
    const uint_t u6 = xh[(size_t)(soff + (i+6)*4)*(B_*D_/2) + colbase];
    const uint_t u7 = xh[(size_t)(soff + (i+7)*4)*(B_*D_/2) + colbase];
    acc0.x += w0*bflo(u0); acc0.y += w0*bfhi(u0);
    acc1.x += w1*bflo(u1); acc1.y += w1*bfhi(u1);
    acc2.x += w2*bflo(u2); acc2.y += w2*bfhi(u2);
    acc3.x += w3*bflo(u3); acc3.y += w3*bfhi(u3);
    acc4.x += w4*bflo(u4); acc4.y += w4*bfhi(u4);
    acc5.x += w5*bflo(u5); acc5.y += w5*bfhi(u5);
    acc6.x += w6*bflo(u6); acc6.y += w6*bfhi(u6);
    acc7.x += w7*bflo(u7); acc7.y += w7*bfhi(u7);
  }
  acc0.x += acc1.x; acc2.x += acc3.x; acc4.x += acc5.x; acc6.x += acc7.x;
  acc0.x += acc2.x; acc4.x += acc6.x; acc0.x += acc4.x;
  acc0.y += acc1.y; acc2.y += acc3.y; acc4.y += acc5.y; acc6.y += acc7.y;
  acc0.y += acc2.y; acc4.y += acc6.y; acc0.y += acc4.y;
  __shared__ float2 buf[4][64];
  buf[soff][uidx] = acc0;
  __syncthreads();
  if (soff == 0){
    float2 r = buf[0][uidx];
    r.x += buf[1][uidx].x + buf[2][uidx].x + buf[3][uidx].x;
    r.y += buf[1][uidx].y + buf[2][uidx].y + buf[3][uidx].y;
    ((float2*)y)[(size_t)b*(D_/2) + d0u + uidx] = r;
  }
}

// ---------------------------------------------------------------------------
extern "C" void kernel_launch(void* const* d_in, const int* in_sizes, int n_in,
                              void* d_out, int out_size, void* d_ws, size_t ws_size,
                              hipStream_t stream){
  const float* x0 = (const float*)d_in[0];
  const float* x1 = (const float*)d_in[1];
  const float* Wq = (const float*)d_in[2];
  const float* bq = (const float*)d_in[3];
  const float* Wv = (const float*)d_in[4];
  const float* bv = (const float*)d_in[5];
  const float* Wc = (const float*)d_in[6];
  const float* bc = (const float*)d_in[7];

  float* out_p = (float*)d_out;              // (B, O)
  float* a_p   = out_p + (size_t)B_*O_;      // (S, B, 1)

  uint_t* xh  = (uint_t*)d_ws;               // bf16 x0 copy: 128 MB
  float* fbase = (float*)((char*)d_ws + (size_t)S_*B_*(D_/2)*sizeof(uint_t));
  float* psum   = fbase;                     // 16*B_*D_
  float* xsum   = fbase + (size_t)16*B_*D_;  // B_*D_
  float* y      = fbase + (size_t)17*B_*D_;  // B_*D_
  float* q      = fbase + (size_t)18*B_*D_;  // B_*D_
  float* c      = fbase + (size_t)19*B_*D_;  // B_*D_
  float* e      = fbase + (size_t)20*B_*D_;  // S_*B_
  float* invcnt = fbase + (size_t)21*B_*D_;  // B_

  k_sum_cvt<<<dim3(B_, 16), 256, 0, stream>>>(x0, psum, xh);
  k_reduce_cnt<<<128, 256, 0, stream>>>(psum, x1, xsum, invcnt);
  k_gemm<false><<<dim3(D_/32, B_/32), 1024, 0, stream>>>(xsum, Wq, bq, invcnt, q, D_);
  k_dote<<<(S_*B_)/4, 256, 0, stream>>>(xh, q, e);
  k_wsum_sm<<<dim3(B_, 8), 256, 0, stream>>>(xh, e, a_p, y);
  k_gemm<false><<<dim3(D_/32, B_/32), 1024, 0, stream>>>(y, Wv, bv, nullptr, c, D_);
  k_gemm<true ><<<dim3(O_/32, B_/32), 1024, 0, stream>>>(c, Wc, bc, nullptr, out_p, O_);
}